// Round 1
// 449.996 us; speedup vs baseline: 1.1978x; 1.1978x over previous
//
#include <hip/hip_runtime.h>
#include <hip/hip_fp16.h>
#include <math.h>

#define NN      65536
#define NE      1048576
#define NPER    1024
#define NGRAPH  64
#define KPER    512
#define IND     192
#define PED     64
#define HID     256
#define LAT     128

// workspace offsets (in 4-byte slots)
#define OFF_CNT     0u          // 65536 int
#define OFF_ROWPTR  65536u      // 65537 int
#define OFF_CUR     132096u     // 65536 int
#define OFF_DINV    198656u     // 65536 f
#define OFF_EPK     264192u     // 1048576 int2 (src, norm) = 2097152 slots
#define OFF_INVWN   2361344u    // 1 f
#define OFF_KEEP    2361360u    // 32768 int
#define OFF_SCORE   2395136u    // 65536 f
#define OFF_WT1     2460672u    // 65536 bf16 (32768 slots): W1^T
#define OFF_WT2     2493440u    // 65536 bf16: [Wmu|Wlv]^T
#define OFF_T0B     2526208u    // 16777216 fp8 (4194304 slots): t0, reused as t1
#define OFF_HB      6720512u    // 16777216 fp8: h
#define OFF_MUB     10914816u   // 8388608 bf16 (4194304 slots)
#define OFF_LVB     15109120u   // 8388608 bf16 (4194304 slots)

// d_out offsets (floats)
#define OUT_MU      4194304
#define OUT_LV      8388608
#define OUT_BATCH   12582912
#define OUT_PERM    12615680

typedef __attribute__((ext_vector_type(8))) short short8;
typedef __attribute__((ext_vector_type(4))) float floatx4;

__device__ __forceinline__ unsigned short f2bf(float f) {
    unsigned int u = __float_as_uint(f);
    u += 0x7FFFu + ((u >> 16) & 1u);
    return (unsigned short)(u >> 16);
}
__device__ __forceinline__ float bf2f(unsigned short u) {
    return __uint_as_float(((unsigned int)u) << 16);
}
// fp8 e5m2 = top byte of fp16 (round-nearest-even on truncate)
__device__ __forceinline__ unsigned char f2e5(float f) {
    unsigned short u = __half_as_ushort(__float2half(f));
    u += (unsigned short)(0x7Fu + ((u >> 8) & 1u));
    return (unsigned char)(u >> 8);
}
__device__ __forceinline__ float e52f(unsigned char c) {
    return __half2float(__ushort_as_half((unsigned short)((unsigned short)c << 8)));
}
// bytes 0,1 of u -> half2 {b0<<8, b1<<8}; bytes 2,3 -> half2 {b2<<8, b3<<8}
__device__ __forceinline__ __half2 e5lo(unsigned int u) {
    return __builtin_bit_cast(__half2, __builtin_amdgcn_perm(u, 0u, 0x05000400u));
}
__device__ __forceinline__ __half2 e5hi(unsigned int u) {
    return __builtin_bit_cast(__half2, __builtin_amdgcn_perm(u, 0u, 0x07000600u));
}

__global__ __launch_bounds__(256) void k_count(const int* __restrict__ ei, int* __restrict__ cnt) {
    int e = blockIdx.x * 256 + threadIdx.x;
    atomicAdd(&cnt[ei[NE + e]], 1);
}

__global__ __launch_bounds__(1024) void k_scan(const int* __restrict__ cnt, int* __restrict__ rp,
                                               float* __restrict__ dinv) {
    __shared__ int part[1024];
    const int t = threadIdx.x;
    const int base = t * 64;
    int loc[64];
#pragma unroll
    for (int i = 0; i < 64; i += 4)
        *(int4*)&loc[i] = *(const int4*)(cnt + base + i);
    int s = 0;
#pragma unroll
    for (int i = 0; i < 64; ++i) s += loc[i];
    part[t] = s;
    __syncthreads();
    for (int d = 1; d < 1024; d <<= 1) {
        int v = (t >= d) ? part[t - d] : 0;
        __syncthreads();
        part[t] += v;
        __syncthreads();
    }
    int run = part[t] - s;
    int rpo[64];
    float dv[64];
#pragma unroll
    for (int i = 0; i < 64; ++i) {
        rpo[i] = run;
        run += loc[i];
        dv[i] = 1.0f / sqrtf((float)(loc[i] + 1));
    }
#pragma unroll
    for (int i = 0; i < 64; i += 4) {
        *(int4*)(rp + base + i) = *(int4*)&rpo[i];
        *(float4*)(dinv + base + i) = *(float4*)&dv[i];
    }
    if (t == 1023) rp[NN] = run;
}

__global__ __launch_bounds__(256) void k_scatter(const int* __restrict__ ei, const int* __restrict__ rp,
                                                 int* __restrict__ cur, const float* __restrict__ dinv,
                                                 int2* __restrict__ epk) {
    int e = blockIdx.x * 256 + threadIdx.x;
    int s = ei[e];
    int d = ei[NE + e];
    int pos = rp[d] + atomicAdd(&cur[d], 1);
    epk[pos] = make_int2(s, __float_as_int(dinv[s] * dinv[d]));
}

__global__ __launch_bounds__(128) void k_wnorm(const float* __restrict__ wp, float* __restrict__ invwn) {
    __shared__ float red[128];
    int t = threadIdx.x;
    float v = wp[t];
    red[t] = v * v;
    __syncthreads();
    for (int s = 64; s > 0; s >>= 1) {
        if (t < s) red[t] += red[t + s];
        __syncthreads();
    }
    if (t == 0) invwn[0] = 1.0f / sqrtf(red[0]);
}

// transpose + bf16-convert weights: wt1[n][k] = W1[k][n]; wt2[n][k] = (Wmu|Wlv)[k][n]
__global__ __launch_bounds__(256) void k_prepw(const float* __restrict__ W1, const float* __restrict__ Wmu,
                                               const float* __restrict__ Wlv, unsigned short* __restrict__ wt1,
                                               unsigned short* __restrict__ wt2) {
    const int n = blockIdx.x, k = threadIdx.x;
    wt1[n * 256 + k] = f2bf(W1[k * 256 + n]);
    wt2[n * 256 + k] = f2bf((n < 128) ? Wmu[k * 128 + n] : Wlv[k * 128 + (n - 128)]);
}

// MFMA bf16 GEMM: C[N,256](fp8 e5m2) = A[N,256] @ B[256,256]
// block: 256 thr = 4 waves, tile M=128 x N=256, K-step 32 (8 steps).
// LDS holds A/B bf16 in fragment order -> conflict-free ds_read_b128.
// MODE 0: A = [x_raw(192,f32) | pe(64,f32)], B = wt1 (W1^T bf16)
// MODE 1: A = h (fp8),                       B = wt2 ([Wmu|Wlv]^T bf16)
template <int MODE>
__global__ __launch_bounds__(256, 2) void k_gemm(const float* __restrict__ A0f, const float* __restrict__ A1f,
                                                 const unsigned char* __restrict__ Ab,
                                                 const unsigned short* __restrict__ Wt,
                                                 unsigned char* __restrict__ Cb) {
    __shared__ unsigned short lds[12288];   // A: 8 tiles*64u*8 = 4096, B: 16*64*8 = 8192
    const int tid = threadIdx.x;
    const int w = __builtin_amdgcn_readfirstlane(tid >> 6);
    const int lane = tid & 63;
    const int l = lane & 15, q = lane >> 4;
    const int Rbase = blockIdx.x * 128;

    const int rs = tid >> 1;       // 0..127 (staging row)
    const int ch = tid & 1;        // k-chunk of 16
    const int stile = rs >> 4, sl = rs & 15, q0 = ch * 2;
    const int uA = (stile * 4 + q0) * 16 + sl;      // A unit idx

    floatx4 acc[16][2];
#pragma unroll
    for (int nt = 0; nt < 16; ++nt) {
        acc[nt][0] = (floatx4)0.0f;
        acc[nt][1] = (floatx4)0.0f;
    }

    for (int ks = 0; ks < 8; ++ks) {
        // ---- stage A (16 values per thread) ----
        unsigned short abuf[16];
        if (MODE == 0) {
            const float* p; int ld, col;
            const int k = ks * 32 + ch * 16;
            if (ks < 6) { p = A0f; ld = IND; col = k; }
            else        { p = A1f; ld = PED; col = k - IND; }
            const float* src = p + (size_t)(Rbase + rs) * ld + col;
#pragma unroll
            for (int j = 0; j < 16; j += 4) {
                const float4 t = *(const float4*)(src + j);
                abuf[j] = f2bf(t.x); abuf[j + 1] = f2bf(t.y);
                abuf[j + 2] = f2bf(t.z); abuf[j + 3] = f2bf(t.w);
            }
        } else {
            const unsigned char* src = Ab + (size_t)(Rbase + rs) * 256 + ks * 32 + ch * 16;
            uint4 pk = *(const uint4*)src;
#pragma unroll
            for (int j = 0; j < 16; ++j) {
                unsigned char c = ((const unsigned char*)&pk)[j];
                abuf[j] = (unsigned short)(__float_as_uint(e52f(c)) >> 16);
            }
        }
        *(uint4*)&lds[uA * 8]        = *(uint4*)&abuf[0];
        *(uint4*)&lds[(uA + 16) * 8] = *(uint4*)&abuf[8];
        // ---- stage B (two 32B chunks per thread) ----
#pragma unroll
        for (int rep = 0; rep < 2; ++rep) {
            const int n = rep * 128 + rs;
            const unsigned short* src = Wt + (size_t)n * 256 + ks * 32 + ch * 16;
            const uint4 w0 = ((const uint4*)src)[0];
            const uint4 w1 = ((const uint4*)src)[1];
            const int uB = ((n >> 4) * 4 + q0) * 16 + (n & 15);
            *(uint4*)&lds[4096 + uB * 8]        = w0;
            *(uint4*)&lds[4096 + (uB + 16) * 8] = w1;
        }
        __syncthreads();
        // ---- compute ----
        const short8 a0 = *(const short8*)&lds[(((2 * w) * 4 + q) * 16 + l) * 8];
        const short8 a1 = *(const short8*)&lds[(((2 * w + 1) * 4 + q) * 16 + l) * 8];
#pragma unroll
        for (int nt = 0; nt < 16; ++nt) {
            const short8 b = *(const short8*)&lds[4096 + ((nt * 4 + q) * 16 + l) * 8];
            acc[nt][0] = __builtin_amdgcn_mfma_f32_16x16x32_bf16(a0, b, acc[nt][0], 0, 0, 0);
            acc[nt][1] = __builtin_amdgcn_mfma_f32_16x16x32_bf16(a1, b, acc[nt][1], 0, 0, 0);
        }
        __syncthreads();
    }

    // ---- store C (fp8) ----
#pragma unroll
    for (int m = 0; m < 2; ++m) {
        const int mt = 2 * w + m;
#pragma unroll
        for (int nt = 0; nt < 16; ++nt) {
            const floatx4 v = acc[nt][m];
            size_t base = (size_t)(Rbase + mt * 16 + q * 4) * 256 + nt * 16 + l;
            Cb[base]       = f2e5(v[0]);
            Cb[base + 256] = f2e5(v[1]);
            Cb[base + 512] = f2e5(v[2]);
            Cb[base + 768] = f2e5(v[3]);
        }
    }
}

// aggregation: one wave per node, 4 fp8 columns per lane, packed half2 FMA accumulate.
// PHASE 0: out = relu(acc + b1) -> fp8 hb
// PHASE 1: cols 0..127 -> mu, 128..255 -> lv (bf16 out); also z & score
template <int PHASE>
__global__ __launch_bounds__(256) void k_agg(const unsigned char* __restrict__ tb, const int* __restrict__ rp,
                                             const int2* __restrict__ epk, const float* __restrict__ dinv,
                                             const float* __restrict__ bias0, const float* __restrict__ bias1,
                                             const float* __restrict__ eps, const float* __restrict__ wp,
                                             const float* __restrict__ invwn, unsigned char* __restrict__ hb,
                                             unsigned short* __restrict__ mub, unsigned short* __restrict__ lvb,
                                             float* __restrict__ score) {
    const int wv = __builtin_amdgcn_readfirstlane(threadIdx.x >> 6);
    const int lane = threadIdx.x & 63;
    const int node = blockIdx.x * 4 + wv;
    const int c0 = lane * 4;
    const float di = dinv[node];

    // self contribution, weight di^2
    const unsigned int vs = *(const unsigned int*)(tb + ((size_t)node << 8) + c0);
    const __half2 ws2 = __float2half2_rn(di * di);
    __half2 a01 = __hmul2(ws2, e5lo(vs));
    __half2 a23 = __hmul2(ws2, e5hi(vs));
    __half2 b01 = __float2half2_rn(0.0f);
    __half2 b23 = __float2half2_rn(0.0f);

    const int beg = rp[node], end = rp[node + 1];
    int p = beg;
    if (p + 4 <= end) {
        int2 e0 = epk[p], e1 = epk[p + 1], e2 = epk[p + 2], e3 = epk[p + 3];
        for (;;) {
            // prefetch next quad (reads may run <=24B past epk end: still inside workspace)
            const int2 f0 = epk[p + 4], f1 = epk[p + 5], f2 = epk[p + 6], f3 = epk[p + 7];
            const int r0 = __builtin_amdgcn_readfirstlane(e0.x);
            const int r1 = __builtin_amdgcn_readfirstlane(e1.x);
            const int r2 = __builtin_amdgcn_readfirstlane(e2.x);
            const int r3 = __builtin_amdgcn_readfirstlane(e3.x);
            const unsigned int v0 = *(const unsigned int*)(tb + ((size_t)r0 << 8) + c0);
            const unsigned int v1 = *(const unsigned int*)(tb + ((size_t)r1 << 8) + c0);
            const unsigned int v2 = *(const unsigned int*)(tb + ((size_t)r2 << 8) + c0);
            const unsigned int v3 = *(const unsigned int*)(tb + ((size_t)r3 << 8) + c0);
            const __half2 w0 = __float2half2_rn(__int_as_float(e0.y));
            const __half2 w1 = __float2half2_rn(__int_as_float(e1.y));
            const __half2 w2 = __float2half2_rn(__int_as_float(e2.y));
            const __half2 w3 = __float2half2_rn(__int_as_float(e3.y));
            a01 = __hfma2(w0, e5lo(v0), a01); a23 = __hfma2(w0, e5hi(v0), a23);
            b01 = __hfma2(w1, e5lo(v1), b01); b23 = __hfma2(w1, e5hi(v1), b23);
            a01 = __hfma2(w2, e5lo(v2), a01); a23 = __hfma2(w2, e5hi(v2), a23);
            b01 = __hfma2(w3, e5lo(v3), b01); b23 = __hfma2(w3, e5hi(v3), b23);
            p += 4;
            if (p + 4 > end) break;
            e0 = f0; e1 = f1; e2 = f2; e3 = f3;
        }
    }
    for (; p < end; ++p) {
        const int2 e = epk[p];
        const int r = __builtin_amdgcn_readfirstlane(e.x);
        const unsigned int v = *(const unsigned int*)(tb + ((size_t)r << 8) + c0);
        const __half2 w2 = __float2half2_rn(__int_as_float(e.y));
        a01 = __hfma2(w2, e5lo(v), a01);
        a23 = __hfma2(w2, e5hi(v), a23);
    }
    a01 = __hadd2(a01, b01);
    a23 = __hadd2(a23, b23);
    const float2 flo = __half22float2(a01);
    const float2 fhi = __half22float2(a23);
    float4 acc = make_float4(flo.x, flo.y, fhi.x, fhi.y);

    if (PHASE == 0) {
        const float4 bb = *(const float4*)(bias0 + c0);
        uchar4 r;
        r.x = f2e5(fmaxf(acc.x + bb.x, 0.0f));
        r.y = f2e5(fmaxf(acc.y + bb.y, 0.0f));
        r.z = f2e5(fmaxf(acc.z + bb.z, 0.0f));
        r.w = f2e5(fmaxf(acc.w + bb.w, 0.0f));
        *(uchar4*)(hb + ((size_t)node << 8) + c0) = r;
    } else {
        const int cb = (lane & 31) * 4;
        const float* bias = (lane < 32) ? bias0 : bias1;
        const float4 bb = *(const float4*)(bias + cb);
        acc.x += bb.x; acc.y += bb.y; acc.z += bb.z; acc.w += bb.w;
        unsigned short* dst = (lane < 32) ? mub : lvb;
        ushort4 st;
        st.x = f2bf(acc.x); st.y = f2bf(acc.y); st.z = f2bf(acc.z); st.w = f2bf(acc.w);
        *(ushort4*)(dst + (size_t)node * 128 + cb) = st;
        float4 l4;
        l4.x = __shfl(acc.x, lane | 32, 64);
        l4.y = __shfl(acc.y, lane | 32, 64);
        l4.z = __shfl(acc.z, lane | 32, 64);
        l4.w = __shfl(acc.w, lane | 32, 64);
        float partial = 0.0f;
        if (lane < 32) {
            const float4 e4 = *(const float4*)(eps + (size_t)node * 128 + cb);
            const float4 w4 = *(const float4*)(wp + cb);
            float zx = fmaf(e4.x, expf(0.5f * l4.x), acc.x);
            float zy = fmaf(e4.y, expf(0.5f * l4.y), acc.y);
            float zz = fmaf(e4.z, expf(0.5f * l4.z), acc.z);
            float zw = fmaf(e4.w, expf(0.5f * l4.w), acc.w);
            partial = zx * w4.x + zy * w4.y + zz * w4.z + zw * w4.w;
        }
        for (int off = 16; off > 0; off >>= 1) partial += __shfl_xor(partial, off, 64);
        if (lane == 0) score[node] = tanhf(partial * invwn[0]);
    }
}

// per-graph bitonic top-k: sort 1024 (score desc, idx asc), emit top 512
__global__ __launch_bounds__(512) void k_topk(const float* __restrict__ score, const int* __restrict__ batch,
                                              int* __restrict__ keep, float* __restrict__ out) {
    __shared__ float sk[1024];
    __shared__ int si[1024];
    const int g = blockIdx.x, t = threadIdx.x;
    for (int i = t; i < 1024; i += 512) {
        sk[i] = score[g * 1024 + i];
        si[i] = i;
    }
    __syncthreads();
    for (int k = 2; k <= 1024; k <<= 1) {
        for (int j = k >> 1; j > 0; j >>= 1) {
            for (int base = 0; base < 1024; base += 512) {
                int i = base + t;
                int ixj = i ^ j;
                if (ixj > i) {
                    float a = sk[i], b = sk[ixj];
                    int ia = si[i], ib = si[ixj];
                    bool before = (a > b) || (a == b && ia < ib);
                    bool up = ((i & k) == 0);
                    bool sw = up ? (!before) : before;
                    if (sw) {
                        sk[i] = b; si[i] = ib;
                        sk[ixj] = a; si[ixj] = ia;
                    }
                }
            }
            __syncthreads();
        }
    }
    if (t < KPER) {
        int node = g * 1024 + si[t];
        keep[g * KPER + t] = node;
        out[OUT_BATCH + g * KPER + t] = (float)batch[node];
        out[OUT_PERM + g * KPER + t] = (float)node;
    }
}

__global__ __launch_bounds__(128) void k_gather(const int* __restrict__ keep,
                                                const unsigned short* __restrict__ mub,
                                                const unsigned short* __restrict__ lvb,
                                                const float* __restrict__ eps,
                                                const float* __restrict__ score, float* __restrict__ out) {
    const int kidx = blockIdx.x;
    const int c = threadIdx.x;
    const int node = keep[kidx];
    const float m = bf2f(mub[(size_t)node * 128 + c]);
    const float l = bf2f(lvb[(size_t)node * 128 + c]);
    const float e = eps[(size_t)node * 128 + c];
    const float z = fmaf(e, expf(0.5f * l), m);
    const float s = score[node];
    out[(size_t)kidx * 128 + c] = z * s;
    out[OUT_MU + (size_t)kidx * 128 + c] = m;
    out[OUT_LV + (size_t)kidx * 128 + c] = l;
}

extern "C" void kernel_launch(void* const* d_in, const int* in_sizes, int n_in,
                              void* d_out, int out_size, void* d_ws, size_t ws_size,
                              hipStream_t stream) {
    (void)in_sizes; (void)n_in; (void)out_size; (void)ws_size;
    const float* x_raw = (const float*)d_in[0];
    const float* pe    = (const float*)d_in[1];
    const int*   ei    = (const int*)d_in[2];
    const int*   batch = (const int*)d_in[3];
    const float* eps   = (const float*)d_in[4];
    const float* W1    = (const float*)d_in[5];
    const float* b1    = (const float*)d_in[6];
    const float* Wmu   = (const float*)d_in[7];
    const float* bmu   = (const float*)d_in[8];
    const float* Wlv   = (const float*)d_in[9];
    const float* blv   = (const float*)d_in[10];
    const float* wp    = (const float*)d_in[11];
    float* ws = (float*)d_ws;
    int*  iws = (int*)d_ws;
    int2* epk = (int2*)(iws + OFF_EPK);
    unsigned short* wt1 = (unsigned short*)(ws + OFF_WT1);
    unsigned short* wt2 = (unsigned short*)(ws + OFF_WT2);
    unsigned char*  t0b = (unsigned char*)(ws + OFF_T0B);
    unsigned char*  hb  = (unsigned char*)(ws + OFF_HB);
    unsigned short* mub = (unsigned short*)(ws + OFF_MUB);
    unsigned short* lvb = (unsigned short*)(ws + OFF_LVB);
    float* out = (float*)d_out;

    hipMemsetAsync(iws + OFF_CNT, 0, 65536 * 4, stream);
    hipMemsetAsync(iws + OFF_CUR, 0, 65536 * 4, stream);

    k_count<<<NE / 256, 256, 0, stream>>>(ei, iws + OFF_CNT);
    k_scan<<<1, 1024, 0, stream>>>(iws + OFF_CNT, iws + OFF_ROWPTR, ws + OFF_DINV);
    k_scatter<<<NE / 256, 256, 0, stream>>>(ei, iws + OFF_ROWPTR, iws + OFF_CUR, ws + OFF_DINV, epk);
    k_wnorm<<<1, 128, 0, stream>>>(wp, ws + OFF_INVWN);
    k_prepw<<<256, 256, 0, stream>>>(W1, Wmu, Wlv, wt1, wt2);

    k_gemm<0><<<NN / 128, 256, 0, stream>>>(x_raw, pe, nullptr, wt1, t0b);
    k_agg<0><<<NN / 4, 256, 0, stream>>>(t0b, iws + OFF_ROWPTR, epk, ws + OFF_DINV,
                                         b1, nullptr, nullptr, nullptr, nullptr,
                                         hb, nullptr, nullptr, nullptr);
    k_gemm<1><<<NN / 128, 256, 0, stream>>>(nullptr, nullptr, hb, wt2, t0b);
    k_agg<1><<<NN / 4, 256, 0, stream>>>(t0b, iws + OFF_ROWPTR, epk, ws + OFF_DINV,
                                         bmu, blv, eps, wp, ws + OFF_INVWN,
                                         nullptr, mub, lvb, ws + OFF_SCORE);
    k_topk<<<NGRAPH, 512, 0, stream>>>(ws + OFF_SCORE, batch, iws + OFF_KEEP, out);
    k_gather<<<NGRAPH * KPER, 128, 0, stream>>>(iws + OFF_KEEP, mub, lvb, eps,
                                                ws + OFF_SCORE, out);
}

// Round 2
// 442.439 us; speedup vs baseline: 1.2183x; 1.0171x over previous
//
#include <hip/hip_runtime.h>
#include <hip/hip_fp16.h>
#include <math.h>

#define NN      65536
#define NE      1048576
#define NPER    1024
#define NGRAPH  64
#define KPER    512
#define IND     192
#define PED     64
#define HID     256
#define LAT     128

// workspace offsets (in 4-byte slots)
#define OFF_CNT     0u          // 65536 int
#define OFF_ROWPTR  65536u      // 65537 int
#define OFF_CUR     132096u     // 65536 int
#define OFF_DINV    198656u     // 65536 f
#define OFF_EPK     264192u     // 1048576 int2 (src, norm) = 2097152 slots
#define OFF_INVWN   2361344u    // 1 f
#define OFF_KEEP    2361360u    // 32768 int
#define OFF_SCORE   2395136u    // 65536 f
#define OFF_WT1     2460672u    // 65536 bf16 (32768 slots): W1^T
#define OFF_WT2     2493440u    // 65536 bf16: [Wmu|Wlv]^T
#define OFF_T0B     2526208u    // 16777216 fp8 (4194304 slots): t0, reused as t1
#define OFF_HB      6720512u    // h bf16: 65536x256 ushort = 8388608 slots; mu/lv overlay after gemm1
#define OFF_MUB     6720512u    // 65536x128 bf16 (4194304 slots)
#define OFF_LVB     10914816u   // 65536x128 bf16 (4194304 slots)
// total ws end: 15109120 slots = 60.4 MB

// d_out offsets (floats)
#define OUT_MU      4194304
#define OUT_LV      8388608
#define OUT_BATCH   12582912
#define OUT_PERM    12615680

typedef __attribute__((ext_vector_type(8))) short short8;
typedef __attribute__((ext_vector_type(4))) float floatx4;

__device__ __forceinline__ unsigned short f2bf(float f) {
    unsigned int u = __float_as_uint(f);
    u += 0x7FFFu + ((u >> 16) & 1u);
    return (unsigned short)(u >> 16);
}
__device__ __forceinline__ float bf2f(unsigned short u) {
    return __uint_as_float(((unsigned int)u) << 16);
}
// pack two f32 -> two bf16 (round-half-up) in one dword via v_perm
__device__ __forceinline__ unsigned int pack2bf(float x, float y) {
    const unsigned int ux = __float_as_uint(x) + 0x8000u;
    const unsigned int uy = __float_as_uint(y) + 0x8000u;
    return __builtin_amdgcn_perm(uy, ux, 0x07060302u);  // [ux>>16 | uy>>16<<16]
}
// fp8 e5m2 = top byte of fp16 (round-nearest-even on truncate)
__device__ __forceinline__ unsigned char f2e5(float f) {
    unsigned short u = __half_as_ushort(__float2half(f));
    u += (unsigned short)(0x7Fu + ((u >> 8) & 1u));
    return (unsigned char)(u >> 8);
}
// store 4 f32 as e5m2 bytes at column stride 256 (rows of C)
__device__ __forceinline__ void store_bf8x4(unsigned char* base, float v0, float v1, float v2, float v3) {
#if __has_builtin(__builtin_amdgcn_cvt_pk_bf8_f32)
    const unsigned int r01 = (unsigned int)__builtin_amdgcn_cvt_pk_bf8_f32(v0, v1, 0, false);
    const unsigned int r23 = (unsigned int)__builtin_amdgcn_cvt_pk_bf8_f32(v2, v3, 0, false);
    base[0]   = (unsigned char)r01;
    base[256] = (unsigned char)(r01 >> 8);
    base[512] = (unsigned char)r23;
    base[768] = (unsigned char)(r23 >> 8);
#else
    base[0] = f2e5(v0); base[256] = f2e5(v1); base[512] = f2e5(v2); base[768] = f2e5(v3);
#endif
}
// bytes 0,1 of u -> half2 {b0<<8, b1<<8}; bytes 2,3 -> half2 {b2<<8, b3<<8}
__device__ __forceinline__ __half2 e5lo(unsigned int u) {
    return __builtin_bit_cast(__half2, __builtin_amdgcn_perm(u, 0u, 0x05000400u));
}
__device__ __forceinline__ __half2 e5hi(unsigned int u) {
    return __builtin_bit_cast(__half2, __builtin_amdgcn_perm(u, 0u, 0x07000600u));
}

__global__ __launch_bounds__(256) void k_count(const int* __restrict__ ei, int* __restrict__ cnt) {
    int e = blockIdx.x * 256 + threadIdx.x;
    atomicAdd(&cnt[ei[NE + e]], 1);
}

__global__ __launch_bounds__(1024) void k_scan(const int* __restrict__ cnt, int* __restrict__ rp,
                                               float* __restrict__ dinv) {
    __shared__ int part[1024];
    const int t = threadIdx.x;
    const int base = t * 64;
    int loc[64];
#pragma unroll
    for (int i = 0; i < 64; i += 4)
        *(int4*)&loc[i] = *(const int4*)(cnt + base + i);
    int s = 0;
#pragma unroll
    for (int i = 0; i < 64; ++i) s += loc[i];
    part[t] = s;
    __syncthreads();
    for (int d = 1; d < 1024; d <<= 1) {
        int v = (t >= d) ? part[t - d] : 0;
        __syncthreads();
        part[t] += v;
        __syncthreads();
    }
    int run = part[t] - s;
    int rpo[64];
    float dv[64];
#pragma unroll
    for (int i = 0; i < 64; ++i) {
        rpo[i] = run;
        run += loc[i];
        dv[i] = 1.0f / sqrtf((float)(loc[i] + 1));
    }
#pragma unroll
    for (int i = 0; i < 64; i += 4) {
        *(int4*)(rp + base + i) = *(int4*)&rpo[i];
        *(float4*)(dinv + base + i) = *(float4*)&dv[i];
    }
    if (t == 1023) rp[NN] = run;
}

__global__ __launch_bounds__(256) void k_scatter(const int* __restrict__ ei, const int* __restrict__ rp,
                                                 int* __restrict__ cur, const float* __restrict__ dinv,
                                                 int2* __restrict__ epk) {
    int e = blockIdx.x * 256 + threadIdx.x;
    int s = ei[e];
    int d = ei[NE + e];
    int pos = rp[d] + atomicAdd(&cur[d], 1);
    epk[pos] = make_int2(s, __float_as_int(dinv[s] * dinv[d]));
}

__global__ __launch_bounds__(128) void k_wnorm(const float* __restrict__ wp, float* __restrict__ invwn) {
    __shared__ float red[128];
    int t = threadIdx.x;
    float v = wp[t];
    red[t] = v * v;
    __syncthreads();
    for (int s = 64; s > 0; s >>= 1) {
        if (t < s) red[t] += red[t + s];
        __syncthreads();
    }
    if (t == 0) invwn[0] = 1.0f / sqrtf(red[0]);
}

// transpose + bf16-convert weights: wt1[n][k] = W1[k][n]; wt2[n][k] = (Wmu|Wlv)[k][n]
__global__ __launch_bounds__(256) void k_prepw(const float* __restrict__ W1, const float* __restrict__ Wmu,
                                               const float* __restrict__ Wlv, unsigned short* __restrict__ wt1,
                                               unsigned short* __restrict__ wt2) {
    const int n = blockIdx.x, k = threadIdx.x;
    wt1[n * 256 + k] = f2bf(W1[k * 256 + n]);
    wt2[n * 256 + k] = f2bf((n < 128) ? Wmu[k * 128 + n] : Wlv[k * 128 + (n - 128)]);
}

// MFMA bf16 GEMM: C[N,256](fp8 e5m2) = A[N,256] @ B[256,256]
// block: 256 thr = 4 waves, tile M=128 x N=256, K-step 32 (8 steps), double-buffered LDS.
// MODE 0: A = [x_raw(192,f32) | pe(64,f32)] packed to bf16 on the fly, B = wt1
// MODE 1: A = h (bf16, direct 16B loads),                              B = wt2
template <int MODE>
__global__ __launch_bounds__(256, 2) void k_gemm(const float* __restrict__ A0f, const float* __restrict__ A1f,
                                                 const unsigned short* __restrict__ Ah,
                                                 const unsigned short* __restrict__ Wt,
                                                 unsigned char* __restrict__ Cb) {
    __shared__ unsigned short lds[2][12288];   // per buf: A 4096, B 8192 ushorts
    const int tid = threadIdx.x;
    const int w = __builtin_amdgcn_readfirstlane(tid >> 6);
    const int lane = tid & 63;
    const int l = lane & 15, q = lane >> 4;
    const int Rbase = blockIdx.x * 128;

    const int rs = tid >> 1;       // 0..127 (staging row)
    const int ch = tid & 1;        // k-chunk of 16
    const int stile = rs >> 4, sl = rs & 15, q0 = ch * 2;
    const int uA = (stile * 4 + q0) * 16 + sl;      // A unit idx

    floatx4 acc[16][2];
#pragma unroll
    for (int nt = 0; nt < 16; ++nt) {
        acc[nt][0] = (floatx4)0.0f;
        acc[nt][1] = (floatx4)0.0f;
    }

    auto stage = [&](int ks, int buf) {
        // ---- A tile ----
        if (MODE == 0) {
            const float* p; int ld, col;
            const int k = ks * 32 + ch * 16;
            if (ks < 6) { p = A0f; ld = IND; col = k; }
            else        { p = A1f; ld = PED; col = k - IND; }
            const float* src = p + (size_t)(Rbase + rs) * ld + col;
            unsigned int pk[8];
#pragma unroll
            for (int j = 0; j < 16; j += 4) {
                const float4 t = *(const float4*)(src + j);
                pk[j / 2]     = pack2bf(t.x, t.y);
                pk[j / 2 + 1] = pack2bf(t.z, t.w);
            }
            *(uint4*)&lds[buf][uA * 8]        = *(uint4*)&pk[0];
            *(uint4*)&lds[buf][(uA + 16) * 8] = *(uint4*)&pk[4];
        } else {
            const unsigned short* src = Ah + (size_t)(Rbase + rs) * 256 + ks * 32 + ch * 16;
            *(uint4*)&lds[buf][uA * 8]        = ((const uint4*)src)[0];
            *(uint4*)&lds[buf][(uA + 16) * 8] = ((const uint4*)src)[1];
        }
        // ---- B tile ----
#pragma unroll
        for (int rep = 0; rep < 2; ++rep) {
            const int n = rep * 128 + rs;
            const unsigned short* srcB = Wt + (size_t)n * 256 + ks * 32 + ch * 16;
            const uint4 w0 = ((const uint4*)srcB)[0];
            const uint4 w1 = ((const uint4*)srcB)[1];
            const int uB = ((n >> 4) * 4 + q0) * 16 + (n & 15);
            *(uint4*)&lds[buf][4096 + uB * 8]        = w0;
            *(uint4*)&lds[buf][4096 + (uB + 16) * 8] = w1;
        }
    };

    stage(0, 0);
    __syncthreads();
#pragma unroll
    for (int ks = 0; ks < 8; ++ks) {
        const int cur = ks & 1;
        if (ks < 7) stage(ks + 1, cur ^ 1);   // prefetch under compute
        const short8 a0 = *(const short8*)&lds[cur][(((2 * w) * 4 + q) * 16 + l) * 8];
        const short8 a1 = *(const short8*)&lds[cur][(((2 * w + 1) * 4 + q) * 16 + l) * 8];
#pragma unroll
        for (int nt = 0; nt < 16; ++nt) {
            const short8 b = *(const short8*)&lds[cur][4096 + ((nt * 4 + q) * 16 + l) * 8];
            acc[nt][0] = __builtin_amdgcn_mfma_f32_16x16x32_bf16(a0, b, acc[nt][0], 0, 0, 0);
            acc[nt][1] = __builtin_amdgcn_mfma_f32_16x16x32_bf16(a1, b, acc[nt][1], 0, 0, 0);
        }
        if (ks < 7) __syncthreads();
    }

    // ---- store C (fp8) ----
#pragma unroll
    for (int m = 0; m < 2; ++m) {
        const int mt = 2 * w + m;
#pragma unroll
        for (int nt = 0; nt < 16; ++nt) {
            const floatx4 v = acc[nt][m];
            unsigned char* base = Cb + (size_t)(Rbase + mt * 16 + q * 4) * 256 + nt * 16 + l;
            store_bf8x4(base, v[0], v[1], v[2], v[3]);
        }
    }
}

// aggregation: one wave per node, 4 fp8 columns per lane, packed half2 FMA, 8-deep pipeline.
// PHASE 0: out = relu(acc + b1) -> bf16 hb
// PHASE 1: cols 0..127 -> mu, 128..255 -> lv (bf16 out); also z & score
template <int PHASE>
__global__ __launch_bounds__(256) void k_agg(const unsigned char* __restrict__ tb, const int* __restrict__ rp,
                                             const int2* __restrict__ epk, const float* __restrict__ dinv,
                                             const float* __restrict__ bias0, const float* __restrict__ bias1,
                                             const float* __restrict__ eps, const float* __restrict__ wp,
                                             const float* __restrict__ invwn, unsigned short* __restrict__ hb,
                                             unsigned short* __restrict__ mub, unsigned short* __restrict__ lvb,
                                             float* __restrict__ score) {
    const int wv = __builtin_amdgcn_readfirstlane(threadIdx.x >> 6);
    const int lane = threadIdx.x & 63;
    const int node = blockIdx.x * 4 + wv;
    const int c0 = lane * 4;
    const float di = dinv[node];
    const unsigned char* tbc = tb + c0;

    // self contribution, weight di^2
    const unsigned int vs = *(const unsigned int*)(tbc + ((size_t)node << 8));
    const __half2 ws2 = __float2half2_rn(di * di);
    __half2 a01 = __hmul2(ws2, e5lo(vs));
    __half2 a23 = __hmul2(ws2, e5hi(vs));
    __half2 b01 = __float2half2_rn(0.0f);
    __half2 b23 = __float2half2_rn(0.0f);

    const int beg = rp[node], end = rp[node + 1];
    int p = beg;
    if (p + 8 <= end) {
        int2 e0 = epk[p],     e1 = epk[p + 1], e2 = epk[p + 2], e3 = epk[p + 3];
        int2 e4 = epk[p + 4], e5 = epk[p + 5], e6 = epk[p + 6], e7 = epk[p + 7];
        for (;;) {
            // prefetch next oct (reads may run <=128B past epk end: still inside workspace)
            const int2 f0 = epk[p + 8],  f1 = epk[p + 9],  f2 = epk[p + 10], f3 = epk[p + 11];
            const int2 f4 = epk[p + 12], f5 = epk[p + 13], f6 = epk[p + 14], f7 = epk[p + 15];
            const unsigned int v0 = *(const unsigned int*)(tbc + ((size_t)__builtin_amdgcn_readfirstlane(e0.x) << 8));
            const unsigned int v1 = *(const unsigned int*)(tbc + ((size_t)__builtin_amdgcn_readfirstlane(e1.x) << 8));
            const unsigned int v2 = *(const unsigned int*)(tbc + ((size_t)__builtin_amdgcn_readfirstlane(e2.x) << 8));
            const unsigned int v3 = *(const unsigned int*)(tbc + ((size_t)__builtin_amdgcn_readfirstlane(e3.x) << 8));
            const unsigned int v4 = *(const unsigned int*)(tbc + ((size_t)__builtin_amdgcn_readfirstlane(e4.x) << 8));
            const unsigned int v5 = *(const unsigned int*)(tbc + ((size_t)__builtin_amdgcn_readfirstlane(e5.x) << 8));
            const unsigned int v6 = *(const unsigned int*)(tbc + ((size_t)__builtin_amdgcn_readfirstlane(e6.x) << 8));
            const unsigned int v7 = *(const unsigned int*)(tbc + ((size_t)__builtin_amdgcn_readfirstlane(e7.x) << 8));
            const __half2 w0 = __float2half2_rn(__int_as_float(e0.y));
            const __half2 w1 = __float2half2_rn(__int_as_float(e1.y));
            const __half2 w2 = __float2half2_rn(__int_as_float(e2.y));
            const __half2 w3 = __float2half2_rn(__int_as_float(e3.y));
            const __half2 w4 = __float2half2_rn(__int_as_float(e4.y));
            const __half2 w5 = __float2half2_rn(__int_as_float(e5.y));
            const __half2 w6 = __float2half2_rn(__int_as_float(e6.y));
            const __half2 w7 = __float2half2_rn(__int_as_float(e7.y));
            a01 = __hfma2(w0, e5lo(v0), a01); a23 = __hfma2(w0, e5hi(v0), a23);
            b01 = __hfma2(w1, e5lo(v1), b01); b23 = __hfma2(w1, e5hi(v1), b23);
            a01 = __hfma2(w2, e5lo(v2), a01); a23 = __hfma2(w2, e5hi(v2), a23);
            b01 = __hfma2(w3, e5lo(v3), b01); b23 = __hfma2(w3, e5hi(v3), b23);
            a01 = __hfma2(w4, e5lo(v4), a01); a23 = __hfma2(w4, e5hi(v4), a23);
            b01 = __hfma2(w5, e5lo(v5), b01); b23 = __hfma2(w5, e5hi(v5), b23);
            a01 = __hfma2(w6, e5lo(v6), a01); a23 = __hfma2(w6, e5hi(v6), a23);
            b01 = __hfma2(w7, e5lo(v7), b01); b23 = __hfma2(w7, e5hi(v7), b23);
            p += 8;
            if (p + 8 > end) break;
            e0 = f0; e1 = f1; e2 = f2; e3 = f3;
            e4 = f4; e5 = f5; e6 = f6; e7 = f7;
        }
    }
    if (p + 4 <= end) {
        const int2 e0 = epk[p], e1 = epk[p + 1], e2 = epk[p + 2], e3 = epk[p + 3];
        const unsigned int v0 = *(const unsigned int*)(tbc + ((size_t)__builtin_amdgcn_readfirstlane(e0.x) << 8));
        const unsigned int v1 = *(const unsigned int*)(tbc + ((size_t)__builtin_amdgcn_readfirstlane(e1.x) << 8));
        const unsigned int v2 = *(const unsigned int*)(tbc + ((size_t)__builtin_amdgcn_readfirstlane(e2.x) << 8));
        const unsigned int v3 = *(const unsigned int*)(tbc + ((size_t)__builtin_amdgcn_readfirstlane(e3.x) << 8));
        const __half2 w0 = __float2half2_rn(__int_as_float(e0.y));
        const __half2 w1 = __float2half2_rn(__int_as_float(e1.y));
        const __half2 w2 = __float2half2_rn(__int_as_float(e2.y));
        const __half2 w3 = __float2half2_rn(__int_as_float(e3.y));
        a01 = __hfma2(w0, e5lo(v0), a01); a23 = __hfma2(w0, e5hi(v0), a23);
        b01 = __hfma2(w1, e5lo(v1), b01); b23 = __hfma2(w1, e5hi(v1), b23);
        a01 = __hfma2(w2, e5lo(v2), a01); a23 = __hfma2(w2, e5hi(v2), a23);
        b01 = __hfma2(w3, e5lo(v3), b01); b23 = __hfma2(w3, e5hi(v3), b23);
        p += 4;
    }
    for (; p < end; ++p) {
        const int2 e = epk[p];
        const unsigned int v = *(const unsigned int*)(tbc + ((size_t)__builtin_amdgcn_readfirstlane(e.x) << 8));
        const __half2 w2 = __float2half2_rn(__int_as_float(e.y));
        a01 = __hfma2(w2, e5lo(v), a01);
        a23 = __hfma2(w2, e5hi(v), a23);
    }
    a01 = __hadd2(a01, b01);
    a23 = __hadd2(a23, b23);
    const float2 flo = __half22float2(a01);
    const float2 fhi = __half22float2(a23);
    float4 acc = make_float4(flo.x, flo.y, fhi.x, fhi.y);

    if (PHASE == 0) {
        const float4 bb = *(const float4*)(bias0 + c0);
        ushort4 r;
        r.x = f2bf(fmaxf(acc.x + bb.x, 0.0f));
        r.y = f2bf(fmaxf(acc.y + bb.y, 0.0f));
        r.z = f2bf(fmaxf(acc.z + bb.z, 0.0f));
        r.w = f2bf(fmaxf(acc.w + bb.w, 0.0f));
        *(ushort4*)(hb + ((size_t)node << 8) + c0) = r;
    } else {
        const int cb = (lane & 31) * 4;
        const float* bias = (lane < 32) ? bias0 : bias1;
        const float4 bb = *(const float4*)(bias + cb);
        acc.x += bb.x; acc.y += bb.y; acc.z += bb.z; acc.w += bb.w;
        unsigned short* dst = (lane < 32) ? mub : lvb;
        ushort4 st;
        st.x = f2bf(acc.x); st.y = f2bf(acc.y); st.z = f2bf(acc.z); st.w = f2bf(acc.w);
        *(ushort4*)(dst + (size_t)node * 128 + cb) = st;
        float4 l4;
        l4.x = __shfl(acc.x, lane | 32, 64);
        l4.y = __shfl(acc.y, lane | 32, 64);
        l4.z = __shfl(acc.z, lane | 32, 64);
        l4.w = __shfl(acc.w, lane | 32, 64);
        float partial = 0.0f;
        if (lane < 32) {
            const float4 e4 = *(const float4*)(eps + (size_t)node * 128 + cb);
            const float4 w4 = *(const float4*)(wp + cb);
            float zx = fmaf(e4.x, expf(0.5f * l4.x), acc.x);
            float zy = fmaf(e4.y, expf(0.5f * l4.y), acc.y);
            float zz = fmaf(e4.z, expf(0.5f * l4.z), acc.z);
            float zw = fmaf(e4.w, expf(0.5f * l4.w), acc.w);
            partial = zx * w4.x + zy * w4.y + zz * w4.z + zw * w4.w;
        }
        for (int off = 16; off > 0; off >>= 1) partial += __shfl_xor(partial, off, 64);
        if (lane == 0) score[node] = tanhf(partial * invwn[0]);
    }
}

// per-graph bitonic top-k: sort 1024 (score desc, idx asc), emit top 512
__global__ __launch_bounds__(512) void k_topk(const float* __restrict__ score, const int* __restrict__ batch,
                                              int* __restrict__ keep, float* __restrict__ out) {
    __shared__ float sk[1024];
    __shared__ int si[1024];
    const int g = blockIdx.x, t = threadIdx.x;
    for (int i = t; i < 1024; i += 512) {
        sk[i] = score[g * 1024 + i];
        si[i] = i;
    }
    __syncthreads();
    for (int k = 2; k <= 1024; k <<= 1) {
        for (int j = k >> 1; j > 0; j >>= 1) {
            for (int base = 0; base < 1024; base += 512) {
                int i = base + t;
                int ixj = i ^ j;
                if (ixj > i) {
                    float a = sk[i], b = sk[ixj];
                    int ia = si[i], ib = si[ixj];
                    bool before = (a > b) || (a == b && ia < ib);
                    bool up = ((i & k) == 0);
                    bool sw = up ? (!before) : before;
                    if (sw) {
                        sk[i] = b; si[i] = ib;
                        sk[ixj] = a; si[ixj] = ia;
                    }
                }
            }
            __syncthreads();
        }
    }
    if (t < KPER) {
        int node = g * 1024 + si[t];
        keep[g * KPER + t] = node;
        out[OUT_BATCH + g * KPER + t] = (float)batch[node];
        out[OUT_PERM + g * KPER + t] = (float)node;
    }
}

__global__ __launch_bounds__(128) void k_gather(const int* __restrict__ keep,
                                                const unsigned short* __restrict__ mub,
                                                const unsigned short* __restrict__ lvb,
                                                const float* __restrict__ eps,
                                                const float* __restrict__ score, float* __restrict__ out) {
    const int kidx = blockIdx.x;
    const int c = threadIdx.x;
    const int node = keep[kidx];
    const float m = bf2f(mub[(size_t)node * 128 + c]);
    const float l = bf2f(lvb[(size_t)node * 128 + c]);
    const float e = eps[(size_t)node * 128 + c];
    const float z = fmaf(e, expf(0.5f * l), m);
    const float s = score[node];
    out[(size_t)kidx * 128 + c] = z * s;
    out[OUT_MU + (size_t)kidx * 128 + c] = m;
    out[OUT_LV + (size_t)kidx * 128 + c] = l;
}

extern "C" void kernel_launch(void* const* d_in, const int* in_sizes, int n_in,
                              void* d_out, int out_size, void* d_ws, size_t ws_size,
                              hipStream_t stream) {
    (void)in_sizes; (void)n_in; (void)out_size; (void)ws_size;
    const float* x_raw = (const float*)d_in[0];
    const float* pe    = (const float*)d_in[1];
    const int*   ei    = (const int*)d_in[2];
    const int*   batch = (const int*)d_in[3];
    const float* eps   = (const float*)d_in[4];
    const float* W1    = (const float*)d_in[5];
    const float* b1    = (const float*)d_in[6];
    const float* Wmu   = (const float*)d_in[7];
    const float* bmu   = (const float*)d_in[8];
    const float* Wlv   = (const float*)d_in[9];
    const float* blv   = (const float*)d_in[10];
    const float* wp    = (const float*)d_in[11];
    float* ws = (float*)d_ws;
    int*  iws = (int*)d_ws;
    int2* epk = (int2*)(iws + OFF_EPK);
    unsigned short* wt1  = (unsigned short*)(ws + OFF_WT1);
    unsigned short* wt2  = (unsigned short*)(ws + OFF_WT2);
    unsigned char*  t0b  = (unsigned char*)(ws + OFF_T0B);
    unsigned short* hb16 = (unsigned short*)(ws + OFF_HB);
    unsigned short* mub  = (unsigned short*)(ws + OFF_MUB);
    unsigned short* lvb  = (unsigned short*)(ws + OFF_LVB);
    float* out = (float*)d_out;

    hipMemsetAsync(iws + OFF_CNT, 0, 65536 * 4, stream);
    hipMemsetAsync(iws + OFF_CUR, 0, 65536 * 4, stream);

    k_count<<<NE / 256, 256, 0, stream>>>(ei, iws + OFF_CNT);
    k_scan<<<1, 1024, 0, stream>>>(iws + OFF_CNT, iws + OFF_ROWPTR, ws + OFF_DINV);
    k_scatter<<<NE / 256, 256, 0, stream>>>(ei, iws + OFF_ROWPTR, iws + OFF_CUR, ws + OFF_DINV, epk);
    k_wnorm<<<1, 128, 0, stream>>>(wp, ws + OFF_INVWN);
    k_prepw<<<256, 256, 0, stream>>>(W1, Wmu, Wlv, wt1, wt2);

    k_gemm<0><<<NN / 128, 256, 0, stream>>>(x_raw, pe, nullptr, wt1, t0b);
    k_agg<0><<<NN / 4, 256, 0, stream>>>(t0b, iws + OFF_ROWPTR, epk, ws + OFF_DINV,
                                         b1, nullptr, nullptr, nullptr, nullptr,
                                         hb16, nullptr, nullptr, nullptr);
    k_gemm<1><<<NN / 128, 256, 0, stream>>>(nullptr, nullptr, hb16, wt2, t0b);
    k_agg<1><<<NN / 4, 256, 0, stream>>>(t0b, iws + OFF_ROWPTR, epk, ws + OFF_DINV,
                                         bmu, blv, eps, wp, ws + OFF_INVWN,
                                         nullptr, mub, lvb, ws + OFF_SCORE);
    k_topk<<<NGRAPH, 512, 0, stream>>>(ws + OFF_SCORE, batch, iws + OFF_KEEP, out);
    k_gather<<<NGRAPH * KPER, 128, 0, stream>>>(iws + OFF_KEEP, mub, lvb, eps,
                                                ws + OFF_SCORE, out);
}

// Round 3
// 439.859 us; speedup vs baseline: 1.2254x; 1.0059x over previous
//
#include <hip/hip_runtime.h>
#include <hip/hip_fp16.h>
#include <math.h>

#define NN      65536
#define NE      1048576
#define NPER    1024
#define NGRAPH  64
#define KPER    512
#define IND     192
#define PED     64
#define HID     256
#define LAT     128

// workspace offsets (in 4-byte slots)
#define OFF_CNT     0u          // 65536 int
#define OFF_ROWPTR  65536u      // 65537 int
#define OFF_CUR     132096u     // 65536 int
#define OFF_DINV    198656u     // 65536 f
#define OFF_EPK     264192u     // 1048576 int2 (src, norm) = 2097152 slots
#define OFF_INVWN   2361344u    // 1 f
#define OFF_KEEP    2361360u    // 32768 int
#define OFF_SCORE   2395136u    // 65536 f
#define OFF_WT1     2460672u    // 65536 bf16 (32768 slots): W1^T
#define OFF_WT2     2493440u    // 65536 bf16: [Wmu|Wlv]^T
#define OFF_T0B     2526208u    // 16777216 fp8 (4194304 slots): t0, reused as t1
#define OFF_HB      6720512u    // h bf16: 65536x256 ushort = 8388608 slots; mu/lv overlay after gemm1
#define OFF_MUB     6720512u    // 65536x128 bf16 (4194304 slots)
#define OFF_LVB     10914816u   // 65536x128 bf16 (4194304 slots)
// total ws end: 15109120 slots = 60.4 MB

// d_out offsets (floats)
#define OUT_MU      4194304
#define OUT_LV      8388608
#define OUT_BATCH   12582912
#define OUT_PERM    12615680

typedef __attribute__((ext_vector_type(8))) short short8;
typedef __attribute__((ext_vector_type(4))) float floatx4;

__device__ __forceinline__ unsigned short f2bf(float f) {
    unsigned int u = __float_as_uint(f);
    u += 0x7FFFu + ((u >> 16) & 1u);
    return (unsigned short)(u >> 16);
}
__device__ __forceinline__ float bf2f(unsigned short u) {
    return __uint_as_float(((unsigned int)u) << 16);
}
// pack two f32 -> two bf16 (round-half-up) in one dword via v_perm
__device__ __forceinline__ unsigned int pack2bf(float x, float y) {
    const unsigned int ux = __float_as_uint(x) + 0x8000u;
    const unsigned int uy = __float_as_uint(y) + 0x8000u;
    return __builtin_amdgcn_perm(uy, ux, 0x07060302u);  // [ux>>16 | uy>>16<<16]
}
// fp8 e5m2 = top byte of fp16 (round-nearest-even on truncate)
__device__ __forceinline__ unsigned char f2e5(float f) {
    unsigned short u = __half_as_ushort(__float2half(f));
    u += (unsigned short)(0x7Fu + ((u >> 8) & 1u));
    return (unsigned char)(u >> 8);
}
// store 4 f32 as e5m2 bytes at column stride 256 (rows of C)
__device__ __forceinline__ void store_bf8x4(unsigned char* base, float v0, float v1, float v2, float v3) {
#if __has_builtin(__builtin_amdgcn_cvt_pk_bf8_f32)
    const unsigned int r01 = (unsigned int)__builtin_amdgcn_cvt_pk_bf8_f32(v0, v1, 0, false);
    const unsigned int r23 = (unsigned int)__builtin_amdgcn_cvt_pk_bf8_f32(v2, v3, 0, false);
    base[0]   = (unsigned char)r01;
    base[256] = (unsigned char)(r01 >> 8);
    base[512] = (unsigned char)r23;
    base[768] = (unsigned char)(r23 >> 8);
#else
    base[0] = f2e5(v0); base[256] = f2e5(v1); base[512] = f2e5(v2); base[768] = f2e5(v3);
#endif
}
// bytes 0,1 of u -> half2 {b0<<8, b1<<8}; bytes 2,3 -> half2 {b2<<8, b3<<8}
__device__ __forceinline__ __half2 e5lo(unsigned int u) {
    return __builtin_bit_cast(__half2, __builtin_amdgcn_perm(u, 0u, 0x05000400u));
}
__device__ __forceinline__ __half2 e5hi(unsigned int u) {
    return __builtin_bit_cast(__half2, __builtin_amdgcn_perm(u, 0u, 0x07000600u));
}

__global__ __launch_bounds__(256) void k_count(const int* __restrict__ ei, int* __restrict__ cnt) {
    int e = blockIdx.x * 256 + threadIdx.x;
    atomicAdd(&cnt[ei[NE + e]], 1);
}

__global__ __launch_bounds__(1024) void k_scan(const int* __restrict__ cnt, int* __restrict__ rp,
                                               float* __restrict__ dinv) {
    __shared__ int part[1024];
    const int t = threadIdx.x;
    const int base = t * 64;
    int loc[64];
#pragma unroll
    for (int i = 0; i < 64; i += 4)
        *(int4*)&loc[i] = *(const int4*)(cnt + base + i);
    int s = 0;
#pragma unroll
    for (int i = 0; i < 64; ++i) s += loc[i];
    part[t] = s;
    __syncthreads();
    for (int d = 1; d < 1024; d <<= 1) {
        int v = (t >= d) ? part[t - d] : 0;
        __syncthreads();
        part[t] += v;
        __syncthreads();
    }
    int run = part[t] - s;
    int rpo[64];
    float dv[64];
#pragma unroll
    for (int i = 0; i < 64; ++i) {
        rpo[i] = run;
        run += loc[i];
        dv[i] = 1.0f / sqrtf((float)(loc[i] + 1));
    }
#pragma unroll
    for (int i = 0; i < 64; i += 4) {
        *(int4*)(rp + base + i) = *(int4*)&rpo[i];
        *(float4*)(dinv + base + i) = *(float4*)&dv[i];
    }
    if (t == 1023) rp[NN] = run;
}

__global__ __launch_bounds__(256) void k_scatter(const int* __restrict__ ei, const int* __restrict__ rp,
                                                 int* __restrict__ cur, const float* __restrict__ dinv,
                                                 int2* __restrict__ epk) {
    int e = blockIdx.x * 256 + threadIdx.x;
    int s = ei[e];
    int d = ei[NE + e];
    int pos = rp[d] + atomicAdd(&cur[d], 1);
    epk[pos] = make_int2(s, __float_as_int(dinv[s] * dinv[d]));
}

__global__ __launch_bounds__(128) void k_wnorm(const float* __restrict__ wp, float* __restrict__ invwn) {
    __shared__ float red[128];
    int t = threadIdx.x;
    float v = wp[t];
    red[t] = v * v;
    __syncthreads();
    for (int s = 64; s > 0; s >>= 1) {
        if (t < s) red[t] += red[t + s];
        __syncthreads();
    }
    if (t == 0) invwn[0] = 1.0f / sqrtf(red[0]);
}

// transpose + bf16-convert weights: wt1[n][k] = W1[k][n]; wt2[n][k] = (Wmu|Wlv)[k][n]
__global__ __launch_bounds__(256) void k_prepw(const float* __restrict__ W1, const float* __restrict__ Wmu,
                                               const float* __restrict__ Wlv, unsigned short* __restrict__ wt1,
                                               unsigned short* __restrict__ wt2) {
    const int n = blockIdx.x, k = threadIdx.x;
    wt1[n * 256 + k] = f2bf(W1[k * 256 + n]);
    wt2[n * 256 + k] = f2bf((n < 128) ? Wmu[k * 128 + n] : Wlv[k * 128 + (n - 128)]);
}

// MFMA bf16 GEMM: C[N,256](fp8 e5m2) = A[N,256] @ B[256,256]
// block: 256 thr = 4 waves, tile M=128 x N=256, K-step 32 (8 steps), double-buffered LDS.
// wave partition: 4 M-tiles x 8 N-tiles each -> 12 ds_read_b128/K-step (was 18).
// MODE 0: A = [x_raw(192,f32) | pe(64,f32)] packed to bf16 on the fly, B = wt1
// MODE 1: A = h (bf16, direct 16B loads),                              B = wt2
template <int MODE>
__global__ __launch_bounds__(256, 2) void k_gemm(const float* __restrict__ A0f, const float* __restrict__ A1f,
                                                 const unsigned short* __restrict__ Ah,
                                                 const unsigned short* __restrict__ Wt,
                                                 unsigned char* __restrict__ Cb) {
    __shared__ unsigned short lds[2][12288];   // per buf: A 4096, B 8192 ushorts
    const int tid = threadIdx.x;
    const int w = __builtin_amdgcn_readfirstlane(tid >> 6);
    const int lane = tid & 63;
    const int l = lane & 15, q = lane >> 4;
    const int Rbase = blockIdx.x * 128;
    const int mtb = (w >> 1) * 4;    // wave's M-tile base (4 tiles)
    const int ntb = (w & 1) * 8;     // wave's N-tile base (8 tiles)

    const int rs = tid >> 1;       // 0..127 (staging row)
    const int ch = tid & 1;        // k-chunk of 16
    const int stile = rs >> 4, sl = rs & 15, q0 = ch * 2;
    const int uA = (stile * 4 + q0) * 16 + sl;      // A unit idx

    floatx4 acc[8][4];
#pragma unroll
    for (int j = 0; j < 8; ++j)
#pragma unroll
        for (int m = 0; m < 4; ++m) acc[j][m] = (floatx4)0.0f;

    auto stage = [&](int ks, int buf) {
        // ---- A tile ----
        if (MODE == 0) {
            const float* p; int ld, col;
            const int k = ks * 32 + ch * 16;
            if (ks < 6) { p = A0f; ld = IND; col = k; }
            else        { p = A1f; ld = PED; col = k - IND; }
            const float* src = p + (size_t)(Rbase + rs) * ld + col;
            unsigned int pk[8];
#pragma unroll
            for (int j = 0; j < 16; j += 4) {
                const float4 t = *(const float4*)(src + j);
                pk[j / 2]     = pack2bf(t.x, t.y);
                pk[j / 2 + 1] = pack2bf(t.z, t.w);
            }
            *(uint4*)&lds[buf][uA * 8]        = *(uint4*)&pk[0];
            *(uint4*)&lds[buf][(uA + 16) * 8] = *(uint4*)&pk[4];
        } else {
            const unsigned short* src = Ah + (size_t)(Rbase + rs) * 256 + ks * 32 + ch * 16;
            *(uint4*)&lds[buf][uA * 8]        = ((const uint4*)src)[0];
            *(uint4*)&lds[buf][(uA + 16) * 8] = ((const uint4*)src)[1];
        }
        // ---- B tile ----
#pragma unroll
        for (int rep = 0; rep < 2; ++rep) {
            const int n = rep * 128 + rs;
            const unsigned short* srcB = Wt + (size_t)n * 256 + ks * 32 + ch * 16;
            const uint4 w0 = ((const uint4*)srcB)[0];
            const uint4 w1 = ((const uint4*)srcB)[1];
            const int uB = ((n >> 4) * 4 + q0) * 16 + (n & 15);
            *(uint4*)&lds[buf][4096 + uB * 8]        = w0;
            *(uint4*)&lds[buf][4096 + (uB + 16) * 8] = w1;
        }
    };

    stage(0, 0);
    __syncthreads();
#pragma unroll
    for (int ks = 0; ks < 8; ++ks) {
        const int cur = ks & 1;
        if (ks < 7) stage(ks + 1, cur ^ 1);   // prefetch under compute
        short8 a[4];
#pragma unroll
        for (int m = 0; m < 4; ++m)
            a[m] = *(const short8*)&lds[cur][(((mtb + m) * 4 + q) * 16 + l) * 8];
#pragma unroll
        for (int j = 0; j < 8; ++j) {
            const short8 b = *(const short8*)&lds[cur][4096 + (((ntb + j) * 4 + q) * 16 + l) * 8];
#pragma unroll
            for (int m = 0; m < 4; ++m)
                acc[j][m] = __builtin_amdgcn_mfma_f32_16x16x32_bf16(a[m], b, acc[j][m], 0, 0, 0);
        }
        if (ks < 7) __syncthreads();
    }

    // ---- store C (fp8) ----
#pragma unroll
    for (int m = 0; m < 4; ++m) {
        const int mt = mtb + m;
#pragma unroll
        for (int j = 0; j < 8; ++j) {
            const int nt = ntb + j;
            const floatx4 v = acc[j][m];
            unsigned char* base = Cb + (size_t)(Rbase + mt * 16 + q * 4) * 256 + nt * 16 + l;
            store_bf8x4(base, v[0], v[1], v[2], v[3]);
        }
    }
}

__device__ __forceinline__ unsigned int gath(const unsigned char* tbc, int srcv) {
    return *(const unsigned int*)(tbc + ((size_t)__builtin_amdgcn_readfirstlane(srcv) << 8));
}

// aggregation: one wave per node, 4 fp8 columns per lane, packed half2 FMA.
// 2-stage software pipeline: meta oct k+2 issued first, gathers oct k+1 issued, compute oct k
// (gathers get a full iteration of latency cover; issue order keeps vmcnt waits partial).
// PHASE 0: out = relu(acc + b1) -> bf16 hb
// PHASE 1: cols 0..127 -> mu, 128..255 -> lv (bf16 out); also z & score
template <int PHASE>
__global__ __launch_bounds__(256) void k_agg(const unsigned char* __restrict__ tb, const int* __restrict__ rp,
                                             const int2* __restrict__ epk, const float* __restrict__ dinv,
                                             const float* __restrict__ bias0, const float* __restrict__ bias1,
                                             const float* __restrict__ eps, const float* __restrict__ wp,
                                             const float* __restrict__ invwn, unsigned short* __restrict__ hb,
                                             unsigned short* __restrict__ mub, unsigned short* __restrict__ lvb,
                                             float* __restrict__ score) {
    const int wv = __builtin_amdgcn_readfirstlane(threadIdx.x >> 6);
    const int lane = threadIdx.x & 63;
    const int node = blockIdx.x * 4 + wv;
    const int c0 = lane * 4;
    const float di = dinv[node];
    const unsigned char* tbc = tb + c0;

    // self contribution, weight di^2
    const unsigned int vs = *(const unsigned int*)(tbc + ((size_t)node << 8));
    const __half2 ws2 = __float2half2_rn(di * di);
    __half2 a01 = __hmul2(ws2, e5lo(vs));
    __half2 a23 = __hmul2(ws2, e5hi(vs));
    __half2 b01 = __float2half2_rn(0.0f);
    __half2 b23 = __float2half2_rn(0.0f);

    const int beg = rp[node], end = rp[node + 1];
    int p = beg;
    if (p + 8 <= end) {
        int2 em[8], en[8];
        unsigned int v[8];
#pragma unroll
        for (int i = 0; i < 8; ++i) em[i] = epk[p + i];          // meta oct0
#pragma unroll
        for (int i = 0; i < 8; ++i) v[i] = gath(tbc, em[i].x);   // gathers oct0 (issue)
#pragma unroll
        for (int i = 0; i < 8; ++i) en[i] = epk[p + 8 + i];      // meta oct1 (overread <=120B past end: in ws)
        while (p + 16 <= end) {
            int2 ef[8];
#pragma unroll
            for (int i = 0; i < 8; ++i) ef[i] = epk[p + 16 + i]; // meta oct k+2 (issue first, no deps)
            unsigned int u[8];
#pragma unroll
            for (int i = 0; i < 8; ++i) u[i] = gath(tbc, en[i].x); // gathers oct k+1
#pragma unroll
            for (int i = 0; i < 8; i += 2) {                     // compute oct k
                const __half2 wA = __float2half2_rn(__int_as_float(em[i].y));
                const __half2 wB = __float2half2_rn(__int_as_float(em[i + 1].y));
                a01 = __hfma2(wA, e5lo(v[i]), a01);     a23 = __hfma2(wA, e5hi(v[i]), a23);
                b01 = __hfma2(wB, e5lo(v[i + 1]), b01); b23 = __hfma2(wB, e5hi(v[i + 1]), b23);
            }
#pragma unroll
            for (int i = 0; i < 8; ++i) { em[i] = en[i]; en[i] = ef[i]; v[i] = u[i]; }
            p += 8;
        }
#pragma unroll
        for (int i = 0; i < 8; i += 2) {                         // drain last full oct
            const __half2 wA = __float2half2_rn(__int_as_float(em[i].y));
            const __half2 wB = __float2half2_rn(__int_as_float(em[i + 1].y));
            a01 = __hfma2(wA, e5lo(v[i]), a01);     a23 = __hfma2(wA, e5hi(v[i]), a23);
            b01 = __hfma2(wB, e5lo(v[i + 1]), b01); b23 = __hfma2(wB, e5hi(v[i + 1]), b23);
        }
        p += 8;
    }
    if (p + 4 <= end) {
        const int2 e0 = epk[p], e1 = epk[p + 1], e2 = epk[p + 2], e3 = epk[p + 3];
        const unsigned int v0 = gath(tbc, e0.x);
        const unsigned int v1 = gath(tbc, e1.x);
        const unsigned int v2 = gath(tbc, e2.x);
        const unsigned int v3 = gath(tbc, e3.x);
        const __half2 w0 = __float2half2_rn(__int_as_float(e0.y));
        const __half2 w1 = __float2half2_rn(__int_as_float(e1.y));
        const __half2 w2 = __float2half2_rn(__int_as_float(e2.y));
        const __half2 w3 = __float2half2_rn(__int_as_float(e3.y));
        a01 = __hfma2(w0, e5lo(v0), a01); a23 = __hfma2(w0, e5hi(v0), a23);
        b01 = __hfma2(w1, e5lo(v1), b01); b23 = __hfma2(w1, e5hi(v1), b23);
        a01 = __hfma2(w2, e5lo(v2), a01); a23 = __hfma2(w2, e5hi(v2), a23);
        b01 = __hfma2(w3, e5lo(v3), b01); b23 = __hfma2(w3, e5hi(v3), b23);
        p += 4;
    }
    for (; p < end; ++p) {
        const int2 e = epk[p];
        const unsigned int v = gath(tbc, e.x);
        const __half2 w2 = __float2half2_rn(__int_as_float(e.y));
        a01 = __hfma2(w2, e5lo(v), a01);
        a23 = __hfma2(w2, e5hi(v), a23);
    }
    a01 = __hadd2(a01, b01);
    a23 = __hadd2(a23, b23);
    const float2 flo = __half22float2(a01);
    const float2 fhi = __half22float2(a23);
    float4 acc = make_float4(flo.x, flo.y, fhi.x, fhi.y);

    if (PHASE == 0) {
        const float4 bb = *(const float4*)(bias0 + c0);
        ushort4 r;
        r.x = f2bf(fmaxf(acc.x + bb.x, 0.0f));
        r.y = f2bf(fmaxf(acc.y + bb.y, 0.0f));
        r.z = f2bf(fmaxf(acc.z + bb.z, 0.0f));
        r.w = f2bf(fmaxf(acc.w + bb.w, 0.0f));
        *(ushort4*)(hb + ((size_t)node << 8) + c0) = r;
    } else {
        const int cb = (lane & 31) * 4;
        const float* bias = (lane < 32) ? bias0 : bias1;
        const float4 bb = *(const float4*)(bias + cb);
        acc.x += bb.x; acc.y += bb.y; acc.z += bb.z; acc.w += bb.w;
        unsigned short* dst = (lane < 32) ? mub : lvb;
        ushort4 st;
        st.x = f2bf(acc.x); st.y = f2bf(acc.y); st.z = f2bf(acc.z); st.w = f2bf(acc.w);
        *(ushort4*)(dst + (size_t)node * 128 + cb) = st;
        float4 l4;
        l4.x = __shfl(acc.x, lane | 32, 64);
        l4.y = __shfl(acc.y, lane | 32, 64);
        l4.z = __shfl(acc.z, lane | 32, 64);
        l4.w = __shfl(acc.w, lane | 32, 64);
        float partial = 0.0f;
        if (lane < 32) {
            const float4 e4 = *(const float4*)(eps + (size_t)node * 128 + cb);
            const float4 w4 = *(const float4*)(wp + cb);
            float zx = fmaf(e4.x, expf(0.5f * l4.x), acc.x);
            float zy = fmaf(e4.y, expf(0.5f * l4.y), acc.y);
            float zz = fmaf(e4.z, expf(0.5f * l4.z), acc.z);
            float zw = fmaf(e4.w, expf(0.5f * l4.w), acc.w);
            partial = zx * w4.x + zy * w4.y + zz * w4.z + zw * w4.w;
        }
        for (int off = 16; off > 0; off >>= 1) partial += __shfl_xor(partial, off, 64);
        if (lane == 0) score[node] = tanhf(partial * invwn[0]);
    }
}

// per-graph bitonic top-k: sort 1024 (score desc, idx asc), emit top 512
__global__ __launch_bounds__(512) void k_topk(const float* __restrict__ score, const int* __restrict__ batch,
                                              int* __restrict__ keep, float* __restrict__ out) {
    __shared__ float sk[1024];
    __shared__ int si[1024];
    const int g = blockIdx.x, t = threadIdx.x;
    for (int i = t; i < 1024; i += 512) {
        sk[i] = score[g * 1024 + i];
        si[i] = i;
    }
    __syncthreads();
    for (int k = 2; k <= 1024; k <<= 1) {
        for (int j = k >> 1; j > 0; j >>= 1) {
            for (int base = 0; base < 1024; base += 512) {
                int i = base + t;
                int ixj = i ^ j;
                if (ixj > i) {
                    float a = sk[i], b = sk[ixj];
                    int ia = si[i], ib = si[ixj];
                    bool before = (a > b) || (a == b && ia < ib);
                    bool up = ((i & k) == 0);
                    bool sw = up ? (!before) : before;
                    if (sw) {
                        sk[i] = b; si[i] = ib;
                        sk[ixj] = a; si[ixj] = ia;
                    }
                }
            }
            __syncthreads();
        }
    }
    if (t < KPER) {
        int node = g * 1024 + si[t];
        keep[g * KPER + t] = node;
        out[OUT_BATCH + g * KPER + t] = (float)batch[node];
        out[OUT_PERM + g * KPER + t] = (float)node;
    }
}

__global__ __launch_bounds__(128) void k_gather(const int* __restrict__ keep,
                                                const unsigned short* __restrict__ mub,
                                                const unsigned short* __restrict__ lvb,
                                                const float* __restrict__ eps,
                                                const float* __restrict__ score, float* __restrict__ out) {
    const int kidx = blockIdx.x;
    const int c = threadIdx.x;
    const int node = keep[kidx];
    const float m = bf2f(mub[(size_t)node * 128 + c]);
    const float l = bf2f(lvb[(size_t)node * 128 + c]);
    const float e = eps[(size_t)node * 128 + c];
    const float z = fmaf(e, expf(0.5f * l), m);
    const float s = score[node];
    out[(size_t)kidx * 128 + c] = z * s;
    out[OUT_MU + (size_t)kidx * 128 + c] = m;
    out[OUT_LV + (size_t)kidx * 128 + c] = l;
}

extern "C" void kernel_launch(void* const* d_in, const int* in_sizes, int n_in,
                              void* d_out, int out_size, void* d_ws, size_t ws_size,
                              hipStream_t stream) {
    (void)in_sizes; (void)n_in; (void)out_size; (void)ws_size;
    const float* x_raw = (const float*)d_in[0];
    const float* pe    = (const float*)d_in[1];
    const int*   ei    = (const int*)d_in[2];
    const int*   batch = (const int*)d_in[3];
    const float* eps   = (const float*)d_in[4];
    const float* W1    = (const float*)d_in[5];
    const float* b1    = (const float*)d_in[6];
    const float* Wmu   = (const float*)d_in[7];
    const float* bmu   = (const float*)d_in[8];
    const float* Wlv   = (const float*)d_in[9];
    const float* blv   = (const float*)d_in[10];
    const float* wp    = (const float*)d_in[11];
    float* ws = (float*)d_ws;
    int*  iws = (int*)d_ws;
    int2* epk = (int2*)(iws + OFF_EPK);
    unsigned short* wt1  = (unsigned short*)(ws + OFF_WT1);
    unsigned short* wt2  = (unsigned short*)(ws + OFF_WT2);
    unsigned char*  t0b  = (unsigned char*)(ws + OFF_T0B);
    unsigned short* hb16 = (unsigned short*)(ws + OFF_HB);
    unsigned short* mub  = (unsigned short*)(ws + OFF_MUB);
    unsigned short* lvb  = (unsigned short*)(ws + OFF_LVB);
    float* out = (float*)d_out;

    hipMemsetAsync(iws + OFF_CNT, 0, 65536 * 4, stream);
    hipMemsetAsync(iws + OFF_CUR, 0, 65536 * 4, stream);

    k_count<<<NE / 256, 256, 0, stream>>>(ei, iws + OFF_CNT);
    k_scan<<<1, 1024, 0, stream>>>(iws + OFF_CNT, iws + OFF_ROWPTR, ws + OFF_DINV);
    k_scatter<<<NE / 256, 256, 0, stream>>>(ei, iws + OFF_ROWPTR, iws + OFF_CUR, ws + OFF_DINV, epk);
    k_wnorm<<<1, 128, 0, stream>>>(wp, ws + OFF_INVWN);
    k_prepw<<<256, 256, 0, stream>>>(W1, Wmu, Wlv, wt1, wt2);

    k_gemm<0><<<NN / 128, 256, 0, stream>>>(x_raw, pe, nullptr, wt1, t0b);
    k_agg<0><<<NN / 4, 256, 0, stream>>>(t0b, iws + OFF_ROWPTR, epk, ws + OFF_DINV,
                                         b1, nullptr, nullptr, nullptr, nullptr,
                                         hb16, nullptr, nullptr, nullptr);
    k_gemm<1><<<NN / 128, 256, 0, stream>>>(nullptr, nullptr, hb16, wt2, t0b);
    k_agg<1><<<NN / 4, 256, 0, stream>>>(t0b, iws + OFF_ROWPTR, epk, ws + OFF_DINV,
                                         bmu, blv, eps, wp, ws + OFF_INVWN,
                                         nullptr, mub, lvb, ws + OFF_SCORE);
    k_topk<<<NGRAPH, 512, 0, stream>>>(ws + OFF_SCORE, batch, iws + OFF_KEEP, out);
    k_gather<<<NGRAPH * KPER, 128, 0, stream>>>(iws + OFF_KEEP, mub, lvb, eps,
                                                ws + OFF_SCORE, out);
}

// Round 4
// 422.265 us; speedup vs baseline: 1.2765x; 1.0417x over previous
//
#include <hip/hip_runtime.h>
#include <hip/hip_fp16.h>
#include <math.h>

#define NN      65536
#define NE      1048576
#define NPER    1024
#define NGRAPH  64
#define KPER    512
#define IND     192
#define PED     64
#define HID     256
#define LAT     128

// workspace offsets (in 4-byte slots)
#define OFF_CNT     0u          // 65536 int
#define OFF_ROWPTR  65536u      // 65537 int
#define OFF_CUR     132096u     // 65536 int
#define OFF_DINV    198656u     // 65536 f
#define OFF_EPK     264192u     // 1048576 int2 (src, norm) = 2097152 slots
#define OFF_INVWN   2361344u    // 1 f
#define OFF_KEEP    2361360u    // 32768 int (also reused as bsum[256] during scan)
#define OFF_SCORE   2395136u    // 65536 f
#define OFF_WT1     2460672u    // 65536 bf16 (32768 slots): W1^T
#define OFF_WT2     2493440u    // 65536 bf16: [Wmu|Wlv]^T
#define OFF_T0B     2526208u    // 16777216 fp8 (4194304 slots): t0, reused as t1
#define OFF_HB      6720512u    // h bf16: 65536x256 ushort = 8388608 slots; mu/lv overlay after gemm1
#define OFF_MUB     6720512u    // 65536x128 bf16 (4194304 slots)
#define OFF_LVB     10914816u   // 65536x128 bf16 (4194304 slots)
// total ws end: 15109120 slots = 60.4 MB

// d_out offsets (floats)
#define OUT_MU      4194304
#define OUT_LV      8388608
#define OUT_BATCH   12582912
#define OUT_PERM    12615680

typedef __attribute__((ext_vector_type(8))) short short8;
typedef __attribute__((ext_vector_type(4))) float floatx4;

__device__ __forceinline__ unsigned short f2bf(float f) {
    unsigned int u = __float_as_uint(f);
    u += 0x7FFFu + ((u >> 16) & 1u);
    return (unsigned short)(u >> 16);
}
__device__ __forceinline__ float bf2f(unsigned short u) {
    return __uint_as_float(((unsigned int)u) << 16);
}
// pack two f32 -> two bf16 (round-half-up) in one dword via v_perm
__device__ __forceinline__ unsigned int pack2bf(float x, float y) {
    const unsigned int ux = __float_as_uint(x) + 0x8000u;
    const unsigned int uy = __float_as_uint(y) + 0x8000u;
    return __builtin_amdgcn_perm(uy, ux, 0x07060302u);  // [ux>>16 | uy>>16<<16]
}
// fp8 e5m2 = top byte of fp16 (round-nearest-even on truncate)
__device__ __forceinline__ unsigned char f2e5(float f) {
    unsigned short u = __half_as_ushort(__float2half(f));
    u += (unsigned short)(0x7Fu + ((u >> 8) & 1u));
    return (unsigned char)(u >> 8);
}
// pack 4 f32 -> 4 e5m2 bytes in one dword (same values as cvt_pk path used before)
__device__ __forceinline__ unsigned int pack4e5(float v0, float v1, float v2, float v3) {
#if __has_builtin(__builtin_amdgcn_cvt_pk_bf8_f32)
    const int t0 = __builtin_amdgcn_cvt_pk_bf8_f32(v0, v1, 0, false);
    return (unsigned int)__builtin_amdgcn_cvt_pk_bf8_f32(v2, v3, t0, true);
#else
    return (unsigned int)f2e5(v0) | ((unsigned int)f2e5(v1) << 8) |
           ((unsigned int)f2e5(v2) << 16) | ((unsigned int)f2e5(v3) << 24);
#endif
}
// bytes 0,1 of u -> half2 {b0<<8, b1<<8}; bytes 2,3 -> half2 {b2<<8, b3<<8}
__device__ __forceinline__ __half2 e5lo(unsigned int u) {
    return __builtin_bit_cast(__half2, __builtin_amdgcn_perm(u, 0u, 0x05000400u));
}
__device__ __forceinline__ __half2 e5hi(unsigned int u) {
    return __builtin_bit_cast(__half2, __builtin_amdgcn_perm(u, 0u, 0x07000600u));
}

__global__ __launch_bounds__(256) void k_count(const int* __restrict__ ei, int* __restrict__ cnt) {
    const int g = blockIdx.x * 256 + threadIdx.x;
    const int4 d4 = *(const int4*)(ei + NE + g * 4);
    atomicAdd(&cnt[d4.x], 1);
    atomicAdd(&cnt[d4.y], 1);
    atomicAdd(&cnt[d4.z], 1);
    atomicAdd(&cnt[d4.w], 1);
}

// 3-phase multi-block exclusive scan of cnt -> rp; also dinv = rsqrt(cnt+1)
__global__ __launch_bounds__(256) void k_scanA(const int* __restrict__ cnt, int* __restrict__ rp,
                                               float* __restrict__ dinv, int* __restrict__ bsum) {
    __shared__ int sh[256];
    const int t = threadIdx.x, b = blockIdx.x;
    const int i = b * 256 + t;
    const int c = cnt[i];
    sh[t] = c;
    __syncthreads();
    for (int d = 1; d < 256; d <<= 1) {
        const int v = (t >= d) ? sh[t - d] : 0;
        __syncthreads();
        sh[t] += v;
        __syncthreads();
    }
    rp[i] = sh[t] - c;                 // local exclusive
    dinv[i] = 1.0f / sqrtf((float)(c + 1));
    if (t == 255) bsum[b] = sh[t];
}

__global__ __launch_bounds__(256) void k_scanB(int* __restrict__ bsum) {
    __shared__ int sh[256];
    const int t = threadIdx.x;
    const int c = bsum[t];
    sh[t] = c;
    __syncthreads();
    for (int d = 1; d < 256; d <<= 1) {
        const int v = (t >= d) ? sh[t - d] : 0;
        __syncthreads();
        sh[t] += v;
        __syncthreads();
    }
    bsum[t] = sh[t] - c;               // exclusive block offsets
}

__global__ __launch_bounds__(256) void k_scanC(int* __restrict__ rp, const int* __restrict__ bsum) {
    const int t = threadIdx.x, b = blockIdx.x;
    const int i = b * 256 + t;
    rp[i] += bsum[b];
    if (i == NN - 1) rp[NN] = NE;
}

__global__ __launch_bounds__(256) void k_scatter(const int* __restrict__ ei, const int* __restrict__ rp,
                                                 int* __restrict__ cur, const float* __restrict__ dinv,
                                                 int2* __restrict__ epk) {
    int e = blockIdx.x * 256 + threadIdx.x;
    int s = ei[e];
    int d = ei[NE + e];
    int pos = rp[d] + atomicAdd(&cur[d], 1);
    epk[pos] = make_int2(s, __float_as_int(dinv[s] * dinv[d]));
}

__global__ __launch_bounds__(128) void k_wnorm(const float* __restrict__ wp, float* __restrict__ invwn) {
    __shared__ float red[128];
    int t = threadIdx.x;
    float v = wp[t];
    red[t] = v * v;
    __syncthreads();
    for (int s = 64; s > 0; s >>= 1) {
        if (t < s) red[t] += red[t + s];
        __syncthreads();
    }
    if (t == 0) invwn[0] = 1.0f / sqrtf(red[0]);
}

// transpose + bf16-convert weights: wt1[n][k] = W1[k][n]; wt2[n][k] = (Wmu|Wlv)[k][n]
__global__ __launch_bounds__(256) void k_prepw(const float* __restrict__ W1, const float* __restrict__ Wmu,
                                               const float* __restrict__ Wlv, unsigned short* __restrict__ wt1,
                                               unsigned short* __restrict__ wt2) {
    const int n = blockIdx.x, k = threadIdx.x;
    wt1[n * 256 + k] = f2bf(W1[k * 256 + n]);
    wt2[n * 256 + k] = f2bf((n < 128) ? Wmu[k * 128 + n] : Wlv[k * 128 + (n - 128)]);
}

// MFMA bf16 GEMM: C[N,256](fp8 e5m2) = A[N,256] @ B[256,256]
// block: 256 thr = 4 waves, tile M=128 x N=256, K-step 32 (8 steps), double-buffered LDS.
// wave partition: 4 M-tiles x 8 N-tiles each -> 12 ds_read_b128/K-step.
// operands SWAPPED in the mfma (b,a): lane's acc quad = 4 CONSECUTIVE columns of one C row
// -> epilogue packs 4 e5m2 bytes into ONE dword store (32 stores/thread vs 128 byte-stores).
// MODE 0: A = [x_raw(192,f32) | pe(64,f32)] packed to bf16 on the fly, B = wt1
// MODE 1: A = h (bf16, direct 16B loads),                              B = wt2
template <int MODE>
__global__ __launch_bounds__(256, 2) void k_gemm(const float* __restrict__ A0f, const float* __restrict__ A1f,
                                                 const unsigned short* __restrict__ Ah,
                                                 const unsigned short* __restrict__ Wt,
                                                 unsigned char* __restrict__ Cb) {
    __shared__ unsigned short lds[2][12288];   // per buf: A 4096, B 8192 ushorts
    const int tid = threadIdx.x;
    const int w = __builtin_amdgcn_readfirstlane(tid >> 6);
    const int lane = tid & 63;
    const int l = lane & 15, q = lane >> 4;
    const int Rbase = blockIdx.x * 128;
    const int mtb = (w >> 1) * 4;    // wave's M-tile base (4 tiles)
    const int ntb = (w & 1) * 8;     // wave's N-tile base (8 tiles)

    const int rs = tid >> 1;       // 0..127 (staging row)
    const int ch = tid & 1;        // k-chunk of 16
    const int stile = rs >> 4, sl = rs & 15, q0 = ch * 2;
    const int uA = (stile * 4 + q0) * 16 + sl;      // A unit idx

    floatx4 acc[8][4];
#pragma unroll
    for (int j = 0; j < 8; ++j)
#pragma unroll
        for (int m = 0; m < 4; ++m) acc[j][m] = (floatx4)0.0f;

    auto stage = [&](int ks, int buf) {
        // ---- A tile ----
        if (MODE == 0) {
            const float* p; int ld, col;
            const int k = ks * 32 + ch * 16;
            if (ks < 6) { p = A0f; ld = IND; col = k; }
            else        { p = A1f; ld = PED; col = k - IND; }
            const float* src = p + (size_t)(Rbase + rs) * ld + col;
            unsigned int pk[8];
#pragma unroll
            for (int j = 0; j < 16; j += 4) {
                const float4 t = *(const float4*)(src + j);
                pk[j / 2]     = pack2bf(t.x, t.y);
                pk[j / 2 + 1] = pack2bf(t.z, t.w);
            }
            *(uint4*)&lds[buf][uA * 8]        = *(uint4*)&pk[0];
            *(uint4*)&lds[buf][(uA + 16) * 8] = *(uint4*)&pk[4];
        } else {
            const unsigned short* src = Ah + (size_t)(Rbase + rs) * 256 + ks * 32 + ch * 16;
            *(uint4*)&lds[buf][uA * 8]        = ((const uint4*)src)[0];
            *(uint4*)&lds[buf][(uA + 16) * 8] = ((const uint4*)src)[1];
        }
        // ---- B tile ----
#pragma unroll
        for (int rep = 0; rep < 2; ++rep) {
            const int n = rep * 128 + rs;
            const unsigned short* srcB = Wt + (size_t)n * 256 + ks * 32 + ch * 16;
            const uint4 w0 = ((const uint4*)srcB)[0];
            const uint4 w1 = ((const uint4*)srcB)[1];
            const int uB = ((n >> 4) * 4 + q0) * 16 + (n & 15);
            *(uint4*)&lds[buf][4096 + uB * 8]        = w0;
            *(uint4*)&lds[buf][4096 + (uB + 16) * 8] = w1;
        }
    };

    stage(0, 0);
    __syncthreads();
#pragma unroll
    for (int ks = 0; ks < 8; ++ks) {
        const int cur = ks & 1;
        if (ks < 7) stage(ks + 1, cur ^ 1);   // prefetch under compute
        short8 a[4];
#pragma unroll
        for (int m = 0; m < 4; ++m)
            a[m] = *(const short8*)&lds[cur][(((mtb + m) * 4 + q) * 16 + l) * 8];
#pragma unroll
        for (int j = 0; j < 8; ++j) {
            const short8 b = *(const short8*)&lds[cur][4096 + (((ntb + j) * 4 + q) * 16 + l) * 8];
#pragma unroll
            for (int m = 0; m < 4; ++m)
                acc[j][m] = __builtin_amdgcn_mfma_f32_16x16x32_bf16(b, a[m], acc[j][m], 0, 0, 0);
        }
        if (ks < 7) __syncthreads();
    }

    // ---- store C (fp8, packed dwords) ----
    // acc[j][m][i] = C[Rbase + (mtb+m)*16 + l][(ntb+j)*16 + q*4 + i]
#pragma unroll
    for (int m = 0; m < 4; ++m) {
        unsigned char* rbase = Cb + (size_t)(Rbase + (mtb + m) * 16 + l) * 256 + q * 4;
#pragma unroll
        for (int j = 0; j < 8; ++j) {
            const floatx4 v = acc[j][m];
            *(unsigned int*)(rbase + (ntb + j) * 16) = pack4e5(v[0], v[1], v[2], v[3]);
        }
    }
}

// aggregation: one wave per node, 4 fp8 columns per lane, packed half2 FMA.
// 2-stage software pipeline; edge meta loaded lane-parallel (1 load/oct) and
// broadcast via v_readlane (values + order identical to scalar path).
// PHASE 0: out = relu(acc + b1) -> bf16 hb
// PHASE 1: cols 0..127 -> mu, 128..255 -> lv (bf16 out); also z & score
template <int PHASE>
__global__ __launch_bounds__(256) void k_agg(const unsigned char* __restrict__ tb, const int* __restrict__ rp,
                                             const int2* __restrict__ epk, const float* __restrict__ dinv,
                                             const float* __restrict__ bias0, const float* __restrict__ bias1,
                                             const float* __restrict__ eps, const float* __restrict__ wp,
                                             const float* __restrict__ invwn, unsigned short* __restrict__ hb,
                                             unsigned short* __restrict__ mub, unsigned short* __restrict__ lvb,
                                             float* __restrict__ score) {
    const int wv = __builtin_amdgcn_readfirstlane(threadIdx.x >> 6);
    const int lane = threadIdx.x & 63;
    const int node = blockIdx.x * 4 + wv;
    const int c0 = lane * 4;
    const float di = dinv[node];
    const unsigned char* tbc = tb + c0;

    // self contribution, weight di^2
    const unsigned int vs = *(const unsigned int*)(tbc + ((size_t)node << 8));
    const __half2 ws2 = __float2half2_rn(di * di);
    __half2 a01 = __hmul2(ws2, e5lo(vs));
    __half2 a23 = __hmul2(ws2, e5hi(vs));
    __half2 b01 = __float2half2_rn(0.0f);
    __half2 b23 = __float2half2_rn(0.0f);

    const int lane8 = lane & 7;
    const int beg = rp[node], end = rp[node + 1];
    int p = beg;
    if (p + 8 <= end) {
        int2 emv = epk[p + lane8];           // meta oct k (lane i holds edge p+i)
        int2 env = epk[p + 8 + lane8];       // meta oct k+1 (overread <=60B past end: in ws)
        unsigned int v[8];
#pragma unroll
        for (int i = 0; i < 8; ++i)
            v[i] = *(const unsigned int*)(tbc + ((size_t)__builtin_amdgcn_readlane(emv.x, i) << 8));
        while (p + 16 <= end) {
            const int2 efv = epk[p + 16 + lane8];   // meta oct k+2 (issue first, no deps)
            unsigned int u[8];
#pragma unroll
            for (int i = 0; i < 8; ++i)             // gathers oct k+1
                u[i] = *(const unsigned int*)(tbc + ((size_t)__builtin_amdgcn_readlane(env.x, i) << 8));
#pragma unroll
            for (int i = 0; i < 8; i += 2) {        // compute oct k
                const __half2 wA = __float2half2_rn(__int_as_float(__builtin_amdgcn_readlane(emv.y, i)));
                const __half2 wB = __float2half2_rn(__int_as_float(__builtin_amdgcn_readlane(emv.y, i + 1)));
                a01 = __hfma2(wA, e5lo(v[i]), a01);     a23 = __hfma2(wA, e5hi(v[i]), a23);
                b01 = __hfma2(wB, e5lo(v[i + 1]), b01); b23 = __hfma2(wB, e5hi(v[i + 1]), b23);
            }
            emv = env; env = efv;
#pragma unroll
            for (int i = 0; i < 8; ++i) v[i] = u[i];
            p += 8;
        }
#pragma unroll
        for (int i = 0; i < 8; i += 2) {             // drain last full oct
            const __half2 wA = __float2half2_rn(__int_as_float(__builtin_amdgcn_readlane(emv.y, i)));
            const __half2 wB = __float2half2_rn(__int_as_float(__builtin_amdgcn_readlane(emv.y, i + 1)));
            a01 = __hfma2(wA, e5lo(v[i]), a01);     a23 = __hfma2(wA, e5hi(v[i]), a23);
            b01 = __hfma2(wB, e5lo(v[i + 1]), b01); b23 = __hfma2(wB, e5hi(v[i + 1]), b23);
        }
        p += 8;
    }
    if (p + 4 <= end) {
        const int2 e0 = epk[p], e1 = epk[p + 1], e2 = epk[p + 2], e3 = epk[p + 3];
        const unsigned int v0 = *(const unsigned int*)(tbc + ((size_t)__builtin_amdgcn_readfirstlane(e0.x) << 8));
        const unsigned int v1 = *(const unsigned int*)(tbc + ((size_t)__builtin_amdgcn_readfirstlane(e1.x) << 8));
        const unsigned int v2 = *(const unsigned int*)(tbc + ((size_t)__builtin_amdgcn_readfirstlane(e2.x) << 8));
        const unsigned int v3 = *(const unsigned int*)(tbc + ((size_t)__builtin_amdgcn_readfirstlane(e3.x) << 8));
        const __half2 w0 = __float2half2_rn(__int_as_float(e0.y));
        const __half2 w1 = __float2half2_rn(__int_as_float(e1.y));
        const __half2 w2 = __float2half2_rn(__int_as_float(e2.y));
        const __half2 w3 = __float2half2_rn(__int_as_float(e3.y));
        a01 = __hfma2(w0, e5lo(v0), a01); a23 = __hfma2(w0, e5hi(v0), a23);
        b01 = __hfma2(w1, e5lo(v1), b01); b23 = __hfma2(w1, e5hi(v1), b23);
        a01 = __hfma2(w2, e5lo(v2), a01); a23 = __hfma2(w2, e5hi(v2), a23);
        b01 = __hfma2(w3, e5lo(v3), b01); b23 = __hfma2(w3, e5hi(v3), b23);
        p += 4;
    }
    for (; p < end; ++p) {
        const int2 e = epk[p];
        const unsigned int v = *(const unsigned int*)(tbc + ((size_t)__builtin_amdgcn_readfirstlane(e.x) << 8));
        const __half2 w2 = __float2half2_rn(__int_as_float(e.y));
        a01 = __hfma2(w2, e5lo(v), a01);
        a23 = __hfma2(w2, e5hi(v), a23);
    }
    a01 = __hadd2(a01, b01);
    a23 = __hadd2(a23, b23);
    const float2 flo = __half22float2(a01);
    const float2 fhi = __half22float2(a23);
    float4 acc = make_float4(flo.x, flo.y, fhi.x, fhi.y);

    if (PHASE == 0) {
        const float4 bb = *(const float4*)(bias0 + c0);
        ushort4 r;
        r.x = f2bf(fmaxf(acc.x + bb.x, 0.0f));
        r.y = f2bf(fmaxf(acc.y + bb.y, 0.0f));
        r.z = f2bf(fmaxf(acc.z + bb.z, 0.0f));
        r.w = f2bf(fmaxf(acc.w + bb.w, 0.0f));
        *(ushort4*)(hb + ((size_t)node << 8) + c0) = r;
    } else {
        const int cb = (lane & 31) * 4;
        const float* bias = (lane < 32) ? bias0 : bias1;
        const float4 bb = *(const float4*)(bias + cb);
        acc.x += bb.x; acc.y += bb.y; acc.z += bb.z; acc.w += bb.w;
        unsigned short* dst = (lane < 32) ? mub : lvb;
        ushort4 st;
        st.x = f2bf(acc.x); st.y = f2bf(acc.y); st.z = f2bf(acc.z); st.w = f2bf(acc.w);
        *(ushort4*)(dst + (size_t)node * 128 + cb) = st;
        float4 l4;
        l4.x = __shfl(acc.x, lane | 32, 64);
        l4.y = __shfl(acc.y, lane | 32, 64);
        l4.z = __shfl(acc.z, lane | 32, 64);
        l4.w = __shfl(acc.w, lane | 32, 64);
        float partial = 0.0f;
        if (lane < 32) {
            const float4 e4 = *(const float4*)(eps + (size_t)node * 128 + cb);
            const float4 w4 = *(const float4*)(wp + cb);
            float zx = fmaf(e4.x, expf(0.5f * l4.x), acc.x);
            float zy = fmaf(e4.y, expf(0.5f * l4.y), acc.y);
            float zz = fmaf(e4.z, expf(0.5f * l4.z), acc.z);
            float zw = fmaf(e4.w, expf(0.5f * l4.w), acc.w);
            partial = zx * w4.x + zy * w4.y + zz * w4.z + zw * w4.w;
        }
        for (int off = 16; off > 0; off >>= 1) partial += __shfl_xor(partial, off, 64);
        if (lane == 0) score[node] = tanhf(partial * invwn[0]);
    }
}

// per-graph bitonic top-k: sort 1024 (score desc, idx asc), emit top 512
__global__ __launch_bounds__(512) void k_topk(const float* __restrict__ score, const int* __restrict__ batch,
                                              int* __restrict__ keep, float* __restrict__ out) {
    __shared__ float sk[1024];
    __shared__ int si[1024];
    const int g = blockIdx.x, t = threadIdx.x;
    for (int i = t; i < 1024; i += 512) {
        sk[i] = score[g * 1024 + i];
        si[i] = i;
    }
    __syncthreads();
    for (int k = 2; k <= 1024; k <<= 1) {
        for (int j = k >> 1; j > 0; j >>= 1) {
            for (int base = 0; base < 1024; base += 512) {
                int i = base + t;
                int ixj = i ^ j;
                if (ixj > i) {
                    float a = sk[i], b = sk[ixj];
                    int ia = si[i], ib = si[ixj];
                    bool before = (a > b) || (a == b && ia < ib);
                    bool up = ((i & k) == 0);
                    bool sw = up ? (!before) : before;
                    if (sw) {
                        sk[i] = b; si[i] = ib;
                        sk[ixj] = a; si[ixj] = ia;
                    }
                }
            }
            __syncthreads();
        }
    }
    if (t < KPER) {
        int node = g * 1024 + si[t];
        keep[g * KPER + t] = node;
        out[OUT_BATCH + g * KPER + t] = (float)batch[node];
        out[OUT_PERM + g * KPER + t] = (float)node;
    }
}

__global__ __launch_bounds__(128) void k_gather(const int* __restrict__ keep,
                                                const unsigned short* __restrict__ mub,
                                                const unsigned short* __restrict__ lvb,
                                                const float* __restrict__ eps,
                                                const float* __restrict__ score, float* __restrict__ out) {
    const int kidx = blockIdx.x;
    const int c = threadIdx.x;
    const int node = keep[kidx];
    const float m = bf2f(mub[(size_t)node * 128 + c]);
    const float l = bf2f(lvb[(size_t)node * 128 + c]);
    const float e = eps[(size_t)node * 128 + c];
    const float z = fmaf(e, expf(0.5f * l), m);
    const float s = score[node];
    out[(size_t)kidx * 128 + c] = z * s;
    out[OUT_MU + (size_t)kidx * 128 + c] = m;
    out[OUT_LV + (size_t)kidx * 128 + c] = l;
}

extern "C" void kernel_launch(void* const* d_in, const int* in_sizes, int n_in,
                              void* d_out, int out_size, void* d_ws, size_t ws_size,
                              hipStream_t stream) {
    (void)in_sizes; (void)n_in; (void)out_size; (void)ws_size;
    const float* x_raw = (const float*)d_in[0];
    const float* pe    = (const float*)d_in[1];
    const int*   ei    = (const int*)d_in[2];
    const int*   batch = (const int*)d_in[3];
    const float* eps   = (const float*)d_in[4];
    const float* W1    = (const float*)d_in[5];
    const float* b1    = (const float*)d_in[6];
    const float* Wmu   = (const float*)d_in[7];
    const float* bmu   = (const float*)d_in[8];
    const float* Wlv   = (const float*)d_in[9];
    const float* blv   = (const float*)d_in[10];
    const float* wp    = (const float*)d_in[11];
    float* ws = (float*)d_ws;
    int*  iws = (int*)d_ws;
    int2* epk = (int2*)(iws + OFF_EPK);
    unsigned short* wt1  = (unsigned short*)(ws + OFF_WT1);
    unsigned short* wt2  = (unsigned short*)(ws + OFF_WT2);
    unsigned char*  t0b  = (unsigned char*)(ws + OFF_T0B);
    unsigned short* hb16 = (unsigned short*)(ws + OFF_HB);
    unsigned short* mub  = (unsigned short*)(ws + OFF_MUB);
    unsigned short* lvb  = (unsigned short*)(ws + OFF_LVB);
    float* out = (float*)d_out;

    hipMemsetAsync(iws + OFF_CNT, 0, 65536 * 4, stream);
    hipMemsetAsync(iws + OFF_CUR, 0, 65536 * 4, stream);

    k_count<<<NE / 1024, 256, 0, stream>>>(ei, iws + OFF_CNT);
    k_scanA<<<256, 256, 0, stream>>>(iws + OFF_CNT, iws + OFF_ROWPTR, ws + OFF_DINV, iws + OFF_KEEP);
    k_scanB<<<1, 256, 0, stream>>>(iws + OFF_KEEP);
    k_scanC<<<256, 256, 0, stream>>>(iws + OFF_ROWPTR, iws + OFF_KEEP);
    k_scatter<<<NE / 256, 256, 0, stream>>>(ei, iws + OFF_ROWPTR, iws + OFF_CUR, ws + OFF_DINV, epk);
    k_wnorm<<<1, 128, 0, stream>>>(wp, ws + OFF_INVWN);
    k_prepw<<<256, 256, 0, stream>>>(W1, Wmu, Wlv, wt1, wt2);

    k_gemm<0><<<NN / 128, 256, 0, stream>>>(x_raw, pe, nullptr, wt1, t0b);
    k_agg<0><<<NN / 4, 256, 0, stream>>>(t0b, iws + OFF_ROWPTR, epk, ws + OFF_DINV,
                                         b1, nullptr, nullptr, nullptr, nullptr,
                                         hb16, nullptr, nullptr, nullptr);
    k_gemm<1><<<NN / 128, 256, 0, stream>>>(nullptr, nullptr, hb16, wt2, t0b);
    k_agg<1><<<NN / 4, 256, 0, stream>>>(t0b, iws + OFF_ROWPTR, epk, ws + OFF_DINV,
                                         bmu, blv, eps, wp, ws + OFF_INVWN,
                                         nullptr, mub, lvb, ws + OFF_SCORE);
    k_topk<<<NGRAPH, 512, 0, stream>>>(ws + OFF_SCORE, batch, iws + OFF_KEEP, out);
    k_gather<<<NGRAPH * KPER, 128, 0, stream>>>(iws + OFF_KEEP, mub, lvb, eps,
                                                ws + OFF_SCORE, out);
}